// Round 1
// baseline (5003.750 us; speedup 1.0000x reference)
//
#include <hip/hip_runtime.h>
#include <cstdint>
#include <cstddef>

// BiRWKV (RWKV-6 bidirectional time-mix), B=4 T=1024 C=768 H=12 D=64 LORA=64.
// Round 0: correctness-first fp32 pipeline.
//   per dir: 5x mixed GEMM (R,K,V,G,lora1) -> lora2(+exp(-exp)) -> sequential
//   scan fused with GroupNorm+silu-gate -> output GEMM (+accumulate+mask).

#define HH   12
#define DD   64
#define CC   768
#define TT   1024
#define BBB  4
#define LR   64
#define BT   (BBB*TT)

// pad_mask dtype is ambiguous (bool bytes vs int32 vs float32) — detect from
// the first element's byte pattern. All-ones mask is handled correctly by
// every branch for its respective true dtype.
__device__ __forceinline__ float mask_val(const void* mp, int idx) {
    const unsigned char* b = (const unsigned char*)mp;
    const int i0 = ((const int*)mp)[0];
    if (i0 == 0x3f800000) {                      // float32 mask
        return ((const float*)mp)[idx] != 0.f ? 1.f : 0.f;
    }
    if ((b[1] | b[2] | b[3]) == 0) {             // int32 mask
        return ((const int*)mp)[idx] != 0 ? 1.f : 0.f;
    }
    return b[idx] ? 1.f : 0.f;                   // bool (1 byte) mask
}

// Generic 64x64x16-tiled fp32 GEMM, 256 threads, 4x4 micro-tile per thread.
// mixA=1: A[s][c] = x[b][t][c] + (x[b][tprev][c]-x[b][t][c])*mu[c], rows s in
// scan order (dir-dependent time mapping), zero shift at ts==0.
// act: 0 none | 1 silu | 2 tanh | 3 exp(-exp(acc+bias[n])) |
//      4 write to out at original time order | 5 add+mask at original order.
__global__ __launch_bounds__(256)
void gemm_kernel(const float* __restrict__ Ap,
                 const float* __restrict__ x,
                 const float* __restrict__ mu,
                 const float* __restrict__ W,
                 const float* __restrict__ bias,
                 const void*  __restrict__ mask,
                 float* __restrict__ out,
                 const int K, const int N, const int dir,
                 const int act, const int mixA)
{
    __shared__ float As[16][68];   // [k][m], padded
    __shared__ float Bs[16][68];   // [k][n], padded
    const int tid = threadIdx.x;
    const int rowbase = blockIdx.x << 6;
    const int colbase = blockIdx.y << 6;
    const int ty = tid >> 4, tx = tid & 15;

    // A-tile load mapping: thread -> (row am, k-quad aq)
    const int am = tid >> 2;
    const int aq = tid & 3;
    const int s  = rowbase + am;          // scan-order row
    const int bb = s >> 10;               // batch (T=1024)
    const int ts = s & (TT - 1);          // scan time
    const int t  = dir ? (TT - 1 - ts) : ts;
    const int tp = dir ? (t + 1) : (t - 1);   // prev token (valid if ts>0)
    // B-tile load mapping
    const int bk = tid >> 4;
    const int bn = (tid & 15) << 2;

    float acc[4][4];
    #pragma unroll
    for (int i = 0; i < 4; ++i)
        #pragma unroll
        for (int j = 0; j < 4; ++j) acc[i][j] = 0.f;

    for (int k0 = 0; k0 < K; k0 += 16) {
        float4 va;
        if (mixA) {
            const int c = k0 + (aq << 2);
            const float4 xa = *reinterpret_cast<const float4*>(
                x + (size_t)(bb * TT + t) * CC + c);
            float4 xp = make_float4(0.f, 0.f, 0.f, 0.f);
            if (ts > 0)
                xp = *reinterpret_cast<const float4*>(
                    x + (size_t)(bb * TT + tp) * CC + c);
            const float4 m4 = *reinterpret_cast<const float4*>(mu + c);
            va.x = fmaf(xp.x - xa.x, m4.x, xa.x);
            va.y = fmaf(xp.y - xa.y, m4.y, xa.y);
            va.z = fmaf(xp.z - xa.z, m4.z, xa.z);
            va.w = fmaf(xp.w - xa.w, m4.w, xa.w);
        } else {
            va = *reinterpret_cast<const float4*>(
                Ap + (size_t)s * K + k0 + (aq << 2));
        }
        const float4 vb = *reinterpret_cast<const float4*>(
            W + (size_t)(k0 + bk) * N + colbase + bn);

        As[(aq << 2) + 0][am] = va.x;
        As[(aq << 2) + 1][am] = va.y;
        As[(aq << 2) + 2][am] = va.z;
        As[(aq << 2) + 3][am] = va.w;
        *reinterpret_cast<float4*>(&Bs[bk][bn]) = vb;
        __syncthreads();

        #pragma unroll
        for (int kk = 0; kk < 16; ++kk) {
            const float4 a  = *reinterpret_cast<const float4*>(&As[kk][ty << 2]);
            const float4 bv = *reinterpret_cast<const float4*>(&Bs[kk][tx << 2]);
            const float av[4]  = {a.x, a.y, a.z, a.w};
            const float bvv[4] = {bv.x, bv.y, bv.z, bv.w};
            #pragma unroll
            for (int i = 0; i < 4; ++i)
                #pragma unroll
                for (int j = 0; j < 4; ++j)
                    acc[i][j] = fmaf(av[i], bvv[j], acc[i][j]);
        }
        __syncthreads();
    }

    // epilogue
    #pragma unroll
    for (int i = 0; i < 4; ++i) {
        const int srow = rowbase + (ty << 2) + i;
        const int ncol = colbase + (tx << 2);
        float v[4];
        #pragma unroll
        for (int j = 0; j < 4; ++j) v[j] = acc[i][j];

        if (act == 1) {                       // silu
            #pragma unroll
            for (int j = 0; j < 4; ++j) v[j] = v[j] / (1.f + expf(-v[j]));
        } else if (act == 2) {                // tanh
            #pragma unroll
            for (int j = 0; j < 4; ++j) v[j] = tanhf(v[j]);
        } else if (act == 3) {                // decay: exp(-exp(acc + w_bias))
            #pragma unroll
            for (int j = 0; j < 4; ++j) v[j] = expf(-expf(v[j] + bias[ncol + j]));
        }

        if (act <= 3) {
            *reinterpret_cast<float4*>(out + (size_t)srow * N + ncol) =
                make_float4(v[0], v[1], v[2], v[3]);
        } else {
            const int b2  = srow >> 10;
            const int ts2 = srow & (TT - 1);
            const int t2  = dir ? (TT - 1 - ts2) : ts2;
            float* op = out + (size_t)(b2 * TT + t2) * CC + ncol;
            if (act == 4) {
                *reinterpret_cast<float4*>(op) = make_float4(v[0], v[1], v[2], v[3]);
            } else {
                const float mv = mask_val(mask, b2 * TT + t2);
                const float4 old = *reinterpret_cast<const float4*>(op);
                *reinterpret_cast<float4*>(op) = make_float4(
                    (old.x + v[0]) * mv, (old.y + v[1]) * mv,
                    (old.z + v[2]) * mv, (old.w + v[3]) * mv);
            }
        }
    }
}

// Sequential WKV scan, one wave per (b,h). Lane e owns state column S[:,e]
// (64 regs). r/k/w/u are wave-uniform -> scalar loads, SGPR operands in FMA.
// Fused per-head GroupNorm + ln affine + silu-gate multiply in the epilogue.
__global__ __launch_bounds__(64)
void scan_kernel(const float* __restrict__ rbuf, const float* __restrict__ kbuf,
                 const float* __restrict__ vbuf, const float* __restrict__ wbuf,
                 const float* __restrict__ gbuf, const float* __restrict__ u,
                 const float* __restrict__ lnw, const float* __restrict__ lnb,
                 float* __restrict__ zbuf, const int dir)
{
    const int h = blockIdx.x;
    const int b = blockIdx.y;
    const int e = threadIdx.x;

    const float* uh = u + (size_t)(dir * HH + h) * DD;
    const float gw = lnw[dir * CC + h * DD + e];
    const float gb = lnb[dir * CC + h * DD + e];

    float S[DD];
    #pragma unroll
    for (int d = 0; d < DD; ++d) S[d] = 0.f;

    size_t base = (size_t)(b * TT) * CC + h * DD;
    for (int ts = 0; ts < TT; ++ts, base += CC) {
        const float ve = vbuf[base + e];
        const float* rr = rbuf + base;
        const float* kk = kbuf + base;
        const float* ww = wbuf + base;
        float y = 0.f;
        #pragma unroll
        for (int d = 0; d < DD; ++d) {
            const float rd = rr[d];           // uniform -> s_load
            const float kd = kk[d];
            const float wd = ww[d];
            const float kv = kd * ve;
            const float tmp = fmaf(uh[d], kv, S[d]);
            y = fmaf(rd, tmp, y);
            S[d] = fmaf(wd, S[d], kv);
        }
        // GroupNorm over the 64 lanes (one head)
        float sum = y, sq = y * y;
        #pragma unroll
        for (int off = 32; off > 0; off >>= 1) {
            sum += __shfl_xor(sum, off);
            sq  += __shfl_xor(sq, off);
        }
        const float mean = sum * (1.f / 64.f);
        const float var  = fmaf(-mean, mean, sq * (1.f / 64.f));
        const float yn   = (y - mean) * rsqrtf(var + 1e-5f) * gw + gb;
        zbuf[base + e] = yn * gbuf[base + e];
    }
}

extern "C" void kernel_launch(void* const* d_in, const int* in_sizes, int n_in,
                              void* d_out, int out_size, void* d_ws, size_t ws_size,
                              hipStream_t stream)
{
    const float* x     = (const float*)d_in[0];
    const void*  mask  = d_in[1];
    const float* mu    = (const float*)d_in[2];
    const float* wbias = (const float*)d_in[3];
    const float* dw1   = (const float*)d_in[4];
    const float* dw2   = (const float*)d_in[5];
    const float* u     = (const float*)d_in[6];
    const float* Wr    = (const float*)d_in[7];
    const float* Wk    = (const float*)d_in[8];
    const float* Wv    = (const float*)d_in[9];
    const float* Wg    = (const float*)d_in[10];
    const float* Wo    = (const float*)d_in[11];
    const float* lnw   = (const float*)d_in[12];
    const float* lnb   = (const float*)d_in[13];
    float* out = (float*)d_out;

    float* ws = (float*)d_ws;
    const size_t NBT = (size_t)BT * CC;
    float* rbuf  = ws;
    float* kbuf  = rbuf  + NBT;
    float* vbuf  = kbuf  + NBT;
    float* wwbuf = vbuf  + NBT;
    float* gbuf  = wwbuf + NBT;
    float* zbuf  = gbuf  + NBT;
    float* lora  = zbuf  + NBT;        // BT*LR floats

    const dim3 blk(256);
    const dim3 gridC(BT / 64, CC / 64);
    const dim3 gridL(BT / 64, LR / 64);

    for (int dir = 0; dir < 2; ++dir) {
        const float* muD = mu + (size_t)dir * 5 * CC;
        const size_t wOff = (size_t)dir * CC * CC;

        gemm_kernel<<<gridC, blk, 0, stream>>>(nullptr, x, muD + 0 * CC, Wr + wOff,
                                               nullptr, nullptr, rbuf, CC, CC, dir, 0, 1);
        gemm_kernel<<<gridC, blk, 0, stream>>>(nullptr, x, muD + 1 * CC, Wk + wOff,
                                               nullptr, nullptr, kbuf, CC, CC, dir, 0, 1);
        gemm_kernel<<<gridC, blk, 0, stream>>>(nullptr, x, muD + 2 * CC, Wv + wOff,
                                               nullptr, nullptr, vbuf, CC, CC, dir, 0, 1);
        gemm_kernel<<<gridC, blk, 0, stream>>>(nullptr, x, muD + 4 * CC, Wg + wOff,
                                               nullptr, nullptr, gbuf, CC, CC, dir, 1, 1);
        gemm_kernel<<<gridL, blk, 0, stream>>>(nullptr, x, muD + 3 * CC,
                                               dw1 + (size_t)dir * CC * LR,
                                               nullptr, nullptr, lora, CC, LR, dir, 2, 1);
        gemm_kernel<<<gridC, blk, 0, stream>>>(lora, nullptr, nullptr,
                                               dw2 + (size_t)dir * LR * CC,
                                               wbias + (size_t)dir * CC, nullptr,
                                               wwbuf, LR, CC, dir, 3, 0);
        scan_kernel<<<dim3(HH, BBB), dim3(64), 0, stream>>>(
            rbuf, kbuf, vbuf, wwbuf, gbuf, u, lnw, lnb, zbuf, dir);
        gemm_kernel<<<gridC, blk, 0, stream>>>(zbuf, nullptr, nullptr, Wo + wOff,
                                               nullptr, mask, out, CC, CC, dir,
                                               dir == 0 ? 4 : 5, 0);
    }
}

// Round 2
// 1124.189 us; speedup vs baseline: 4.4510x; 4.4510x over previous
//
#include <hip/hip_runtime.h>
#include <cstdint>
#include <cstddef>

// BiRWKV (RWKV-6 bidirectional time-mix), B=4 T=1024 C=768 H=12 D=64 LORA=64.
// Round 2: chunked parallel scan (passes A/B/C). GEMMs unchanged fp32.

#define HH   12
#define DD   64
#define CC   768
#define TT   1024
#define BBB  4
#define LR   64
#define BT   (BBB*TT)
#define LCH  64            // chunk length
#define NCH  (TT/LCH)      // 16 chunks

// pad_mask dtype detect (bool bytes vs int32 vs float32).
__device__ __forceinline__ float mask_val(const void* mp, int idx) {
    const unsigned char* b = (const unsigned char*)mp;
    const int i0 = ((const int*)mp)[0];
    if (i0 == 0x3f800000) {
        return ((const float*)mp)[idx] != 0.f ? 1.f : 0.f;
    }
    if ((b[1] | b[2] | b[3]) == 0) {
        return ((const int*)mp)[idx] != 0 ? 1.f : 0.f;
    }
    return b[idx] ? 1.f : 0.f;
}

// Generic 64x64x16-tiled fp32 GEMM, 256 threads, 4x4 micro-tile per thread.
__global__ __launch_bounds__(256)
void gemm_kernel(const float* __restrict__ Ap,
                 const float* __restrict__ x,
                 const float* __restrict__ mu,
                 const float* __restrict__ W,
                 const float* __restrict__ bias,
                 const void*  __restrict__ mask,
                 float* __restrict__ out,
                 const int K, const int N, const int dir,
                 const int act, const int mixA)
{
    __shared__ float As[16][68];
    __shared__ float Bs[16][68];
    const int tid = threadIdx.x;
    const int rowbase = blockIdx.x << 6;
    const int colbase = blockIdx.y << 6;
    const int ty = tid >> 4, tx = tid & 15;

    const int am = tid >> 2;
    const int aq = tid & 3;
    const int s  = rowbase + am;
    const int bb = s >> 10;
    const int ts = s & (TT - 1);
    const int t  = dir ? (TT - 1 - ts) : ts;
    const int tp = dir ? (t + 1) : (t - 1);
    const int bk = tid >> 4;
    const int bn = (tid & 15) << 2;

    float acc[4][4];
    #pragma unroll
    for (int i = 0; i < 4; ++i)
        #pragma unroll
        for (int j = 0; j < 4; ++j) acc[i][j] = 0.f;

    for (int k0 = 0; k0 < K; k0 += 16) {
        float4 va;
        if (mixA) {
            const int c = k0 + (aq << 2);
            const float4 xa = *reinterpret_cast<const float4*>(
                x + (size_t)(bb * TT + t) * CC + c);
            float4 xp = make_float4(0.f, 0.f, 0.f, 0.f);
            if (ts > 0)
                xp = *reinterpret_cast<const float4*>(
                    x + (size_t)(bb * TT + tp) * CC + c);
            const float4 m4 = *reinterpret_cast<const float4*>(mu + c);
            va.x = fmaf(xp.x - xa.x, m4.x, xa.x);
            va.y = fmaf(xp.y - xa.y, m4.y, xa.y);
            va.z = fmaf(xp.z - xa.z, m4.z, xa.z);
            va.w = fmaf(xp.w - xa.w, m4.w, xa.w);
        } else {
            va = *reinterpret_cast<const float4*>(
                Ap + (size_t)s * K + k0 + (aq << 2));
        }
        const float4 vb = *reinterpret_cast<const float4*>(
            W + (size_t)(k0 + bk) * N + colbase + bn);

        As[(aq << 2) + 0][am] = va.x;
        As[(aq << 2) + 1][am] = va.y;
        As[(aq << 2) + 2][am] = va.z;
        As[(aq << 2) + 3][am] = va.w;
        *reinterpret_cast<float4*>(&Bs[bk][bn]) = vb;
        __syncthreads();

        #pragma unroll
        for (int kk = 0; kk < 16; ++kk) {
            const float4 a  = *reinterpret_cast<const float4*>(&As[kk][ty << 2]);
            const float4 bv = *reinterpret_cast<const float4*>(&Bs[kk][tx << 2]);
            const float av[4]  = {a.x, a.y, a.z, a.w};
            const float bvv[4] = {bv.x, bv.y, bv.z, bv.w};
            #pragma unroll
            for (int i = 0; i < 4; ++i)
                #pragma unroll
                for (int j = 0; j < 4; ++j)
                    acc[i][j] = fmaf(av[i], bvv[j], acc[i][j]);
        }
        __syncthreads();
    }

    #pragma unroll
    for (int i = 0; i < 4; ++i) {
        const int srow = rowbase + (ty << 2) + i;
        const int ncol = colbase + (tx << 2);
        float v[4];
        #pragma unroll
        for (int j = 0; j < 4; ++j) v[j] = acc[i][j];

        if (act == 1) {
            #pragma unroll
            for (int j = 0; j < 4; ++j) v[j] = v[j] / (1.f + expf(-v[j]));
        } else if (act == 2) {
            #pragma unroll
            for (int j = 0; j < 4; ++j) v[j] = tanhf(v[j]);
        } else if (act == 3) {
            #pragma unroll
            for (int j = 0; j < 4; ++j) v[j] = expf(-expf(v[j] + bias[ncol + j]));
        }

        if (act <= 3) {
            *reinterpret_cast<float4*>(out + (size_t)srow * N + ncol) =
                make_float4(v[0], v[1], v[2], v[3]);
        } else {
            const int b2  = srow >> 10;
            const int ts2 = srow & (TT - 1);
            const int t2  = dir ? (TT - 1 - ts2) : ts2;
            float* op = out + (size_t)(b2 * TT + t2) * CC + ncol;
            if (act == 4) {
                *reinterpret_cast<float4*>(op) = make_float4(v[0], v[1], v[2], v[3]);
            } else {
                const float mv = mask_val(mask, b2 * TT + t2);
                const float4 old = *reinterpret_cast<const float4*>(op);
                *reinterpret_cast<float4*>(op) = make_float4(
                    (old.x + v[0]) * mv, (old.y + v[1]) * mv,
                    (old.z + v[2]) * mv, (old.w + v[3]) * mv);
            }
        }
    }
}

// ---------------- chunked scan ----------------
// Pass A: per chunk, local state from zero + decay product P.
// One wave per (chunk, h, b). Lane e owns state column S[d][e].
__global__ __launch_bounds__(64)
void scanA_kernel(const float* __restrict__ kbuf, const float* __restrict__ vbuf,
                  const float* __restrict__ wbuf,
                  float* __restrict__ SL, float* __restrict__ Pbuf)
{
    __shared__ float lk[LCH * DD], lw[LCH * DD], lv[LCH * DD];
    const int c = blockIdx.x, h = blockIdx.y, b = blockIdx.z;
    const int e = threadIdx.x;
    const int rowq = e >> 4;
    const int col  = (e & 15) << 2;

    const size_t gbase = (size_t)(b * TT + c * LCH) * CC + h * DD;
    #pragma unroll
    for (int r4 = 0; r4 < 16; ++r4) {
        const int row = (r4 << 2) + rowq;
        const size_t ga = gbase + (size_t)row * CC + col;
        *reinterpret_cast<float4*>(&lk[row * DD + col]) =
            *reinterpret_cast<const float4*>(kbuf + ga);
        *reinterpret_cast<float4*>(&lw[row * DD + col]) =
            *reinterpret_cast<const float4*>(wbuf + ga);
        *reinterpret_cast<float4*>(&lv[row * DD + col]) =
            *reinterpret_cast<const float4*>(vbuf + ga);
    }
    __syncthreads();

    float S[DD];
    #pragma unroll
    for (int d = 0; d < DD; ++d) S[d] = 0.f;
    float P = 1.f;

    for (int t = 0; t < LCH; ++t) {
        const float ve = lv[t * DD + e];
        P *= lw[t * DD + e];
        #pragma unroll
        for (int d4 = 0; d4 < 16; ++d4) {
            const float4 k4 = *reinterpret_cast<const float4*>(&lk[t * DD + (d4 << 2)]);
            const float4 w4 = *reinterpret_cast<const float4*>(&lw[t * DD + (d4 << 2)]);
            S[(d4 << 2) + 0] = fmaf(w4.x, S[(d4 << 2) + 0], k4.x * ve);
            S[(d4 << 2) + 1] = fmaf(w4.y, S[(d4 << 2) + 1], k4.y * ve);
            S[(d4 << 2) + 2] = fmaf(w4.z, S[(d4 << 2) + 2], k4.z * ve);
            S[(d4 << 2) + 3] = fmaf(w4.w, S[(d4 << 2) + 3], k4.w * ve);
        }
    }

    float* slot = SL + (size_t)((c * BBB + b) * HH + h) * DD * DD;
    #pragma unroll
    for (int d = 0; d < DD; ++d) slot[d * DD + e] = S[d];
    Pbuf[(size_t)((c * BBB + b) * HH + h) * DD + e] = P;
}

// Pass B: sequential over chunks; in-place slot shift:
// slot c := S_before(c+1) = P(c) * S_before(c) + S_local(c).
// Grid (H, B), 256 threads: wave w owns d in [w*16, w*16+16), lane e column.
__global__ __launch_bounds__(256)
void scanB_kernel(float* __restrict__ SL, const float* __restrict__ Pbuf)
{
    const int h = blockIdx.x, b = blockIdx.y;
    const int e  = threadIdx.x & 63;
    const int dg = threadIdx.x >> 6;   // 0..3

    float S[16];
    #pragma unroll
    for (int i = 0; i < 16; ++i) S[i] = 0.f;

    for (int c = 0; c < NCH; ++c) {
        float* slot = SL + (size_t)((c * BBB + b) * HH + h) * DD * DD;
        const float* pp = Pbuf + (size_t)((c * BBB + b) * HH + h) * DD;
        #pragma unroll
        for (int i = 0; i < 16; ++i) {
            const int d = dg * 16 + i;
            const float sl = slot[d * DD + e];
            S[i] = fmaf(pp[d], S[i], sl);
            slot[d * DD + e] = S[i];
        }
    }
}

// Pass C: per chunk, full recurrence from S_before with y output,
// fused GroupNorm + silu-gate. Chunk c>0 reads slot c-1; c==0 starts at 0.
__global__ __launch_bounds__(64)
void scanC_kernel(const float* __restrict__ rbuf, const float* __restrict__ kbuf,
                  const float* __restrict__ vbuf, const float* __restrict__ wbuf,
                  const float* __restrict__ gbuf, const float* __restrict__ SL,
                  const float* __restrict__ u, const float* __restrict__ lnw,
                  const float* __restrict__ lnb, float* __restrict__ zbuf,
                  const int dir)
{
    __shared__ float lr[LCH * DD], lk[LCH * DD], lw[LCH * DD];
    const int c = blockIdx.x, h = blockIdx.y, b = blockIdx.z;
    const int e = threadIdx.x;
    const int rowq = e >> 4;
    const int col  = (e & 15) << 2;

    const size_t gbase = (size_t)(b * TT + c * LCH) * CC + h * DD;
    #pragma unroll
    for (int r4 = 0; r4 < 16; ++r4) {
        const int row = (r4 << 2) + rowq;
        const size_t ga = gbase + (size_t)row * CC + col;
        *reinterpret_cast<float4*>(&lr[row * DD + col]) =
            *reinterpret_cast<const float4*>(rbuf + ga);
        *reinterpret_cast<float4*>(&lk[row * DD + col]) =
            *reinterpret_cast<const float4*>(kbuf + ga);
        *reinterpret_cast<float4*>(&lw[row * DD + col]) =
            *reinterpret_cast<const float4*>(wbuf + ga);
    }
    __syncthreads();

    const float ue = u[(size_t)(dir * HH + h) * DD + e];
    const float gw = lnw[dir * CC + h * DD + e];
    const float gb = lnb[dir * CC + h * DD + e];

    float S[DD];
    if (c == 0) {
        #pragma unroll
        for (int d = 0; d < DD; ++d) S[d] = 0.f;
    } else {
        const float* slot = SL + (size_t)(((c - 1) * BBB + b) * HH + h) * DD * DD;
        #pragma unroll
        for (int d = 0; d < DD; ++d) S[d] = slot[d * DD + e];
    }

    for (int t = 0; t < LCH; ++t) {
        const float ve = vbuf[gbase + (size_t)t * CC + e];
        // coef = sum_d r[d]*u[d]*k[d]  (covers the u ⊙ kv bonus term)
        float coef = lr[t * DD + e] * ue * lk[t * DD + e];
        #pragma unroll
        for (int off = 32; off > 0; off >>= 1) coef += __shfl_xor(coef, off);

        float y0 = 0.f, y1 = 0.f, y2 = 0.f, y3 = 0.f;
        #pragma unroll
        for (int d4 = 0; d4 < 16; ++d4) {
            const float4 r4 = *reinterpret_cast<const float4*>(&lr[t * DD + (d4 << 2)]);
            const float4 k4 = *reinterpret_cast<const float4*>(&lk[t * DD + (d4 << 2)]);
            const float4 w4 = *reinterpret_cast<const float4*>(&lw[t * DD + (d4 << 2)]);
            y0 = fmaf(r4.x, S[(d4 << 2) + 0], y0);
            y1 = fmaf(r4.y, S[(d4 << 2) + 1], y1);
            y2 = fmaf(r4.z, S[(d4 << 2) + 2], y2);
            y3 = fmaf(r4.w, S[(d4 << 2) + 3], y3);
            S[(d4 << 2) + 0] = fmaf(w4.x, S[(d4 << 2) + 0], k4.x * ve);
            S[(d4 << 2) + 1] = fmaf(w4.y, S[(d4 << 2) + 1], k4.y * ve);
            S[(d4 << 2) + 2] = fmaf(w4.z, S[(d4 << 2) + 2], k4.z * ve);
            S[(d4 << 2) + 3] = fmaf(w4.w, S[(d4 << 2) + 3], k4.w * ve);
        }
        float y = ((y0 + y1) + (y2 + y3)) + coef * ve;

        // per-head GroupNorm across the 64 lanes
        float sum = y, sq = y * y;
        #pragma unroll
        for (int off = 32; off > 0; off >>= 1) {
            sum += __shfl_xor(sum, off);
            sq  += __shfl_xor(sq, off);
        }
        const float mean = sum * (1.f / 64.f);
        const float var  = fmaf(-mean, mean, sq * (1.f / 64.f));
        const float yn   = (y - mean) * rsqrtf(var + 1e-5f) * gw + gb;
        zbuf[gbase + (size_t)t * CC + e] = yn * gbuf[gbase + (size_t)t * CC + e];
    }
}

// Fallback sequential scan (used only if ws_size is too small for SL/P).
__global__ __launch_bounds__(64)
void scan_kernel(const float* __restrict__ rbuf, const float* __restrict__ kbuf,
                 const float* __restrict__ vbuf, const float* __restrict__ wbuf,
                 const float* __restrict__ gbuf, const float* __restrict__ u,
                 const float* __restrict__ lnw, const float* __restrict__ lnb,
                 float* __restrict__ zbuf, const int dir)
{
    const int h = blockIdx.x;
    const int b = blockIdx.y;
    const int e = threadIdx.x;

    const float* uh = u + (size_t)(dir * HH + h) * DD;
    const float gw = lnw[dir * CC + h * DD + e];
    const float gb = lnb[dir * CC + h * DD + e];

    float S[DD];
    #pragma unroll
    for (int d = 0; d < DD; ++d) S[d] = 0.f;

    size_t base = (size_t)(b * TT) * CC + h * DD;
    for (int ts = 0; ts < TT; ++ts, base += CC) {
        const float ve = vbuf[base + e];
        const float* rr = rbuf + base;
        const float* kk = kbuf + base;
        const float* ww = wbuf + base;
        float y = 0.f;
        #pragma unroll
        for (int d = 0; d < DD; ++d) {
            const float rd = rr[d];
            const float kd = kk[d];
            const float wd = ww[d];
            const float kv = kd * ve;
            const float tmp = fmaf(uh[d], kv, S[d]);
            y = fmaf(rd, tmp, y);
            S[d] = fmaf(wd, S[d], kv);
        }
        float sum = y, sq = y * y;
        #pragma unroll
        for (int off = 32; off > 0; off >>= 1) {
            sum += __shfl_xor(sum, off);
            sq  += __shfl_xor(sq, off);
        }
        const float mean = sum * (1.f / 64.f);
        const float var  = fmaf(-mean, mean, sq * (1.f / 64.f));
        const float yn   = (y - mean) * rsqrtf(var + 1e-5f) * gw + gb;
        zbuf[base + e] = yn * gbuf[base + e];
    }
}

extern "C" void kernel_launch(void* const* d_in, const int* in_sizes, int n_in,
                              void* d_out, int out_size, void* d_ws, size_t ws_size,
                              hipStream_t stream)
{
    const float* x     = (const float*)d_in[0];
    const void*  mask  = d_in[1];
    const float* mu    = (const float*)d_in[2];
    const float* wbias = (const float*)d_in[3];
    const float* dw1   = (const float*)d_in[4];
    const float* dw2   = (const float*)d_in[5];
    const float* u     = (const float*)d_in[6];
    const float* Wr    = (const float*)d_in[7];
    const float* Wk    = (const float*)d_in[8];
    const float* Wv    = (const float*)d_in[9];
    const float* Wg    = (const float*)d_in[10];
    const float* Wo    = (const float*)d_in[11];
    const float* lnw   = (const float*)d_in[12];
    const float* lnb   = (const float*)d_in[13];
    float* out = (float*)d_out;

    float* ws = (float*)d_ws;
    const size_t NBT = (size_t)BT * CC;
    float* rbuf  = ws;
    float* kbuf  = rbuf  + NBT;
    float* vbuf  = kbuf  + NBT;
    float* wwbuf = vbuf  + NBT;
    float* gbuf  = wwbuf + NBT;
    float* zbuf  = gbuf  + NBT;
    float* lora  = zbuf  + NBT;                     // BT*LR
    float* SL    = lora  + (size_t)BT * LR;         // NCH*B*H*D*D
    float* Pbuf  = SL    + (size_t)NCH * BBB * HH * DD * DD;
    const size_t needed = (size_t)(Pbuf + (size_t)NCH * BBB * HH * DD - ws) * 4;
    const bool chunked = ws_size >= needed;

    const dim3 blk(256);
    const dim3 gridC(BT / 64, CC / 64);
    const dim3 gridL(BT / 64, LR / 64);

    for (int dir = 0; dir < 2; ++dir) {
        const float* muD = mu + (size_t)dir * 5 * CC;
        const size_t wOff = (size_t)dir * CC * CC;

        gemm_kernel<<<gridC, blk, 0, stream>>>(nullptr, x, muD + 0 * CC, Wr + wOff,
                                               nullptr, nullptr, rbuf, CC, CC, dir, 0, 1);
        gemm_kernel<<<gridC, blk, 0, stream>>>(nullptr, x, muD + 1 * CC, Wk + wOff,
                                               nullptr, nullptr, kbuf, CC, CC, dir, 0, 1);
        gemm_kernel<<<gridC, blk, 0, stream>>>(nullptr, x, muD + 2 * CC, Wv + wOff,
                                               nullptr, nullptr, vbuf, CC, CC, dir, 0, 1);
        gemm_kernel<<<gridC, blk, 0, stream>>>(nullptr, x, muD + 4 * CC, Wg + wOff,
                                               nullptr, nullptr, gbuf, CC, CC, dir, 1, 1);
        gemm_kernel<<<gridL, blk, 0, stream>>>(nullptr, x, muD + 3 * CC,
                                               dw1 + (size_t)dir * CC * LR,
                                               nullptr, nullptr, lora, CC, LR, dir, 2, 1);
        gemm_kernel<<<gridC, blk, 0, stream>>>(lora, nullptr, nullptr,
                                               dw2 + (size_t)dir * LR * CC,
                                               wbias + (size_t)dir * CC, nullptr,
                                               wwbuf, LR, CC, dir, 3, 0);
        if (chunked) {
            scanA_kernel<<<dim3(NCH, HH, BBB), dim3(64), 0, stream>>>(
                kbuf, vbuf, wwbuf, SL, Pbuf);
            scanB_kernel<<<dim3(HH, BBB), dim3(256), 0, stream>>>(SL, Pbuf);
            scanC_kernel<<<dim3(NCH, HH, BBB), dim3(64), 0, stream>>>(
                rbuf, kbuf, vbuf, wwbuf, gbuf, SL, u, lnw, lnb, zbuf, dir);
        } else {
            scan_kernel<<<dim3(HH, BBB), dim3(64), 0, stream>>>(
                rbuf, kbuf, vbuf, wwbuf, gbuf, u, lnw, lnb, zbuf, dir);
        }
        gemm_kernel<<<gridC, blk, 0, stream>>>(zbuf, nullptr, nullptr, Wo + wOff,
                                               nullptr, mask, out, CC, CC, dir,
                                               dir == 0 ? 4 : 5, 0);
    }
}

// Round 4
// 659.130 us; speedup vs baseline: 7.5915x; 1.7056x over previous
//
#include <hip/hip_runtime.h>
#include <cstdint>
#include <cstddef>

// BiRWKV (RWKV-6 bidirectional time-mix), B=4 T=1024 C=768 H=12 D=64 LORA=64.
// Round 4: fp16 MFMA (10-bit mantissa vs bf16's 7 — same MFMA rate) for the 5
// big GEMMs per dir; decay (lora) path stays fp32; chunked scan unchanged;
// scanC emits z in fp16 for the output GEMM.

#define HH   12
#define DD   64
#define CC   768
#define TT   1024
#define BBB  4
#define LR   64
#define BT   (BBB*TT)
#define LCH  64
#define NCH  (TT/LCH)
#define WSQ  (CC*CC)

typedef unsigned short u16;
typedef _Float16 f16x8 __attribute__((ext_vector_type(8)));  // 8 f16 (4 VGPRs)
typedef float f32x4 __attribute__((ext_vector_type(4)));     // MFMA accumulator

__device__ __forceinline__ u16 f2h(float f) {                // RNE fp32->fp16
    const _Float16 h = (_Float16)f;
    return __builtin_bit_cast(u16, h);
}
__device__ __forceinline__ float h2f(u16 h) {
    return (float)__builtin_bit_cast(_Float16, h);
}

// pad_mask dtype detect (bool bytes vs int32 vs float32).
__device__ __forceinline__ float mask_val(const void* mp, int idx) {
    const unsigned char* b = (const unsigned char*)mp;
    const int i0 = ((const int*)mp)[0];
    if (i0 == 0x3f800000) {
        return ((const float*)mp)[idx] != 0.f ? 1.f : 0.f;
    }
    if ((b[1] | b[2] | b[3]) == 0) {
        return ((const int*)mp)[idx] != 0 ? 1.f : 0.f;
    }
    return b[idx] ? 1.f : 0.f;
}

// ---------------- prepass: weight transpose-convert, x convert ----------------
struct TP10 { const float* src[10]; };

// src [K=768][N=768] f32 -> dst[j][N][K] fp16 (W^T, k-contiguous rows)
__global__ __launch_bounds__(256)
void transpose_conv(TP10 tj, u16* __restrict__ dst)
{
    __shared__ float sh[32][33];
    const int j = blockIdx.z;
    const float* __restrict__ src = tj.src[j];
    u16* __restrict__ d = dst + (size_t)j * WSQ;
    const int n0 = blockIdx.x << 5, k0 = blockIdx.y << 5;
    const int tx = threadIdx.x & 31, ty = threadIdx.x >> 5;
    #pragma unroll
    for (int i = 0; i < 4; ++i)
        sh[ty + (i << 3)][tx] = src[(size_t)(k0 + ty + (i << 3)) * CC + n0 + tx];
    __syncthreads();
    #pragma unroll
    for (int i = 0; i < 4; ++i)
        d[(size_t)(n0 + ty + (i << 3)) * CC + k0 + tx] =
            f2h(sh[tx][ty + (i << 3)]);
}

__global__ __launch_bounds__(256)
void convert_x(const float* __restrict__ x, u16* __restrict__ xb)
{
    const size_t off = ((size_t)blockIdx.x * 256 + threadIdx.x) * 8;
    const float4 a = *reinterpret_cast<const float4*>(x + off);
    const float4 b = *reinterpret_cast<const float4*>(x + off + 4);
    uint4 w;
    w.x = (unsigned)f2h(a.x) | ((unsigned)f2h(a.y) << 16);
    w.y = (unsigned)f2h(a.z) | ((unsigned)f2h(a.w) << 16);
    w.z = (unsigned)f2h(b.x) | ((unsigned)f2h(b.y) << 16);
    w.w = (unsigned)f2h(b.z) | ((unsigned)f2h(b.w) << 16);
    *reinterpret_cast<uint4*>(xb + off) = w;
}

// ---------------- fp16 MFMA GEMM ----------------
// 64x64 tile, BK=64, 256 threads = 4 waves (2x2), 16x16x32 MFMA, 2x2 frags/wave.
// A: mixA ? token-shift lerp of fp16 x (rows in scan order) : fp16 buffer [BT][K].
// B: Wt fp16 [N][K]. Output f32.
// act: 0 none | 1 silu | 4 store at original time order | 5 add+mask at orig.
__global__ __launch_bounds__(256)
void gemm_mfma(const u16* __restrict__ Ab, const u16* __restrict__ xb,
               const float* __restrict__ mu, const u16* __restrict__ Wt,
               const void* __restrict__ mask, float* __restrict__ out,
               const int K, const int N, const int dir, const int act,
               const int mixA)
{
    __shared__ __align__(16) u16 Als[64][72];
    __shared__ __align__(16) u16 Bls[64][72];
    const int tid = threadIdx.x;
    const int rowbase = blockIdx.x << 6;
    const int colbase = blockIdx.y << 6;
    const int lane = tid & 63;
    const int wid = tid >> 6;
    const int wr = (wid >> 1) << 5;     // wave row offset: 0 / 32
    const int wc = (wid & 1) << 5;      // wave col offset: 0 / 32
    const int lm = lane & 15;
    const int lk = (lane >> 4) << 3;    // k offset of fragment (0,8,16,24)

    f32x4 acc[2][2] = {};

    for (int k0 = 0; k0 < K; k0 += 64) {
        #pragma unroll
        for (int it = 0; it < 2; ++it) {
            const int c   = tid + (it << 8);
            const int row = c >> 3;
            const int kq  = (c & 7) << 3;
            // B tile: Bls[n][k]
            *reinterpret_cast<uint4*>(&Bls[row][kq]) =
                *reinterpret_cast<const uint4*>(
                    Wt + (size_t)(colbase + row) * K + k0 + kq);
            if (mixA) {
                const int s  = rowbase + row;
                const int bb = s >> 10, ts = s & (TT - 1);
                const int t  = dir ? (TT - 1 - ts) : ts;
                const int tp = dir ? (t + 1) : (t - 1);
                const uint4 xa4 = *reinterpret_cast<const uint4*>(
                    xb + (size_t)(bb * TT + t) * CC + k0 + kq);
                uint4 xp4 = make_uint4(0u, 0u, 0u, 0u);
                if (ts > 0)
                    xp4 = *reinterpret_cast<const uint4*>(
                        xb + (size_t)(bb * TT + tp) * CC + k0 + kq);
                const u16* as = reinterpret_cast<const u16*>(&xa4);
                const u16* ps = reinterpret_cast<const u16*>(&xp4);
                const float4 m0 = *reinterpret_cast<const float4*>(mu + k0 + kq);
                const float4 m1 = *reinterpret_cast<const float4*>(mu + k0 + kq + 4);
                const float mm[8] = {m0.x, m0.y, m0.z, m0.w,
                                     m1.x, m1.y, m1.z, m1.w};
                uint4 w;
                unsigned rr[4];
                #pragma unroll
                for (int q = 0; q < 4; ++q) {
                    const float a0 = h2f(as[2 * q]);
                    const float a1 = h2f(as[2 * q + 1]);
                    const float p0 = h2f(ps[2 * q]);
                    const float p1 = h2f(ps[2 * q + 1]);
                    const float v0 = fmaf(p0 - a0, mm[2 * q], a0);
                    const float v1 = fmaf(p1 - a1, mm[2 * q + 1], a1);
                    rr[q] = (unsigned)f2h(v0) | ((unsigned)f2h(v1) << 16);
                }
                w.x = rr[0]; w.y = rr[1]; w.z = rr[2]; w.w = rr[3];
                *reinterpret_cast<uint4*>(&Als[row][kq]) = w;
            } else {
                *reinterpret_cast<uint4*>(&Als[row][kq]) =
                    *reinterpret_cast<const uint4*>(
                        Ab + (size_t)(rowbase + row) * K + k0 + kq);
            }
        }
        __syncthreads();
        #pragma unroll
        for (int ks = 0; ks < 2; ++ks) {
            const int ko = (ks << 5) + lk;
            const f16x8 a0 = *reinterpret_cast<const f16x8*>(&Als[wr + lm][ko]);
            const f16x8 a1 = *reinterpret_cast<const f16x8*>(&Als[wr + 16 + lm][ko]);
            const f16x8 b0 = *reinterpret_cast<const f16x8*>(&Bls[wc + lm][ko]);
            const f16x8 b1 = *reinterpret_cast<const f16x8*>(&Bls[wc + 16 + lm][ko]);
            acc[0][0] = __builtin_amdgcn_mfma_f32_16x16x32_f16(a0, b0, acc[0][0], 0, 0, 0);
            acc[0][1] = __builtin_amdgcn_mfma_f32_16x16x32_f16(a0, b1, acc[0][1], 0, 0, 0);
            acc[1][0] = __builtin_amdgcn_mfma_f32_16x16x32_f16(a1, b0, acc[1][0], 0, 0, 0);
            acc[1][1] = __builtin_amdgcn_mfma_f32_16x16x32_f16(a1, b1, acc[1][1], 0, 0, 0);
        }
        __syncthreads();
    }

    // epilogue: D[m=(lane>>4)*4+r][n=lane&15] per 16x16 fragment
    #pragma unroll
    for (int mi = 0; mi < 2; ++mi) {
        #pragma unroll
        for (int r = 0; r < 4; ++r) {
            const int srow = rowbase + wr + mi * 16 + ((lane >> 4) << 2) + r;
            float v0 = acc[mi][0][r];
            float v1 = acc[mi][1][r];
            if (act == 1) {
                v0 = v0 / (1.f + expf(-v0));
                v1 = v1 / (1.f + expf(-v1));
            }
            if (act <= 1) {
                out[(size_t)srow * N + colbase + wc + lm]      = v0;
                out[(size_t)srow * N + colbase + wc + 16 + lm] = v1;
            } else {
                const int b2  = srow >> 10;
                const int ts2 = srow & (TT - 1);
                const int t2  = dir ? (TT - 1 - ts2) : ts2;
                float* op = out + (size_t)(b2 * TT + t2) * CC + colbase + wc + lm;
                if (act == 4) {
                    op[0]  = v0;
                    op[16] = v1;
                } else {
                    const float mv = mask_val(mask, b2 * TT + t2);
                    op[0]  = (op[0]  + v0) * mv;
                    op[16] = (op[16] + v1) * mv;
                }
            }
        }
    }
}

// ---------------- fp32 GEMM (decay/LoRA path only) ----------------
// act: 2 tanh | 3 exp(-exp(acc+bias[n]))
__global__ __launch_bounds__(256)
void gemm_kernel(const float* __restrict__ Ap,
                 const float* __restrict__ x,
                 const float* __restrict__ mu,
                 const float* __restrict__ W,
                 const float* __restrict__ bias,
                 float* __restrict__ out,
                 const int K, const int N, const int dir,
                 const int act, const int mixA)
{
    __shared__ float As[16][68];
    __shared__ float Bs[16][68];
    const int tid = threadIdx.x;
    const int rowbase = blockIdx.x << 6;
    const int colbase = blockIdx.y << 6;
    const int ty = tid >> 4, tx = tid & 15;

    const int am = tid >> 2;
    const int aq = tid & 3;
    const int s  = rowbase + am;
    const int bb = s >> 10;
    const int ts = s & (TT - 1);
    const int t  = dir ? (TT - 1 - ts) : ts;
    const int tp = dir ? (t + 1) : (t - 1);
    const int bk = tid >> 4;
    const int bn = (tid & 15) << 2;

    float acc[4][4];
    #pragma unroll
    for (int i = 0; i < 4; ++i)
        #pragma unroll
        for (int j = 0; j < 4; ++j) acc[i][j] = 0.f;

    for (int k0 = 0; k0 < K; k0 += 16) {
        float4 va;
        if (mixA) {
            const int c = k0 + (aq << 2);
            const float4 xa = *reinterpret_cast<const float4*>(
                x + (size_t)(bb * TT + t) * CC + c);
            float4 xp = make_float4(0.f, 0.f, 0.f, 0.f);
            if (ts > 0)
                xp = *reinterpret_cast<const float4*>(
                    x + (size_t)(bb * TT + tp) * CC + c);
            const float4 m4 = *reinterpret_cast<const float4*>(mu + c);
            va.x = fmaf(xp.x - xa.x, m4.x, xa.x);
            va.y = fmaf(xp.y - xa.y, m4.y, xa.y);
            va.z = fmaf(xp.z - xa.z, m4.z, xa.z);
            va.w = fmaf(xp.w - xa.w, m4.w, xa.w);
        } else {
            va = *reinterpret_cast<const float4*>(
                Ap + (size_t)s * K + k0 + (aq << 2));
        }
        const float4 vb = *reinterpret_cast<const float4*>(
            W + (size_t)(k0 + bk) * N + colbase + bn);

        As[(aq << 2) + 0][am] = va.x;
        As[(aq << 2) + 1][am] = va.y;
        As[(aq << 2) + 2][am] = va.z;
        As[(aq << 2) + 3][am] = va.w;
        *reinterpret_cast<float4*>(&Bs[bk][bn]) = vb;
        __syncthreads();

        #pragma unroll
        for (int kk = 0; kk < 16; ++kk) {
            const float4 a  = *reinterpret_cast<const float4*>(&As[kk][ty << 2]);
            const float4 bv = *reinterpret_cast<const float4*>(&Bs[kk][tx << 2]);
            const float av[4]  = {a.x, a.y, a.z, a.w};
            const float bvv[4] = {bv.x, bv.y, bv.z, bv.w};
            #pragma unroll
            for (int i = 0; i < 4; ++i)
                #pragma unroll
                for (int j = 0; j < 4; ++j)
                    acc[i][j] = fmaf(av[i], bvv[j], acc[i][j]);
        }
        __syncthreads();
    }

    #pragma unroll
    for (int i = 0; i < 4; ++i) {
        const int srow = rowbase + (ty << 2) + i;
        const int ncol = colbase + (tx << 2);
        float v[4];
        #pragma unroll
        for (int j = 0; j < 4; ++j) v[j] = acc[i][j];
        if (act == 2) {
            #pragma unroll
            for (int j = 0; j < 4; ++j) v[j] = tanhf(v[j]);
        } else if (act == 3) {
            #pragma unroll
            for (int j = 0; j < 4; ++j) v[j] = expf(-expf(v[j] + bias[ncol + j]));
        }
        *reinterpret_cast<float4*>(out + (size_t)srow * N + ncol) =
            make_float4(v[0], v[1], v[2], v[3]);
    }
}

// ---------------- chunked scan (A/B/C) ----------------
__global__ __launch_bounds__(64)
void scanA_kernel(const float* __restrict__ kbuf, const float* __restrict__ vbuf,
                  const float* __restrict__ wbuf,
                  float* __restrict__ SL, float* __restrict__ Pbuf)
{
    __shared__ float lk[LCH * DD], lw[LCH * DD], lv[LCH * DD];
    const int c = blockIdx.x, h = blockIdx.y, b = blockIdx.z;
    const int e = threadIdx.x;
    const int rowq = e >> 4;
    const int col  = (e & 15) << 2;

    const size_t gbase = (size_t)(b * TT + c * LCH) * CC + h * DD;
    #pragma unroll
    for (int r4 = 0; r4 < 16; ++r4) {
        const int row = (r4 << 2) + rowq;
        const size_t ga = gbase + (size_t)row * CC + col;
        *reinterpret_cast<float4*>(&lk[row * DD + col]) =
            *reinterpret_cast<const float4*>(kbuf + ga);
        *reinterpret_cast<float4*>(&lw[row * DD + col]) =
            *reinterpret_cast<const float4*>(wbuf + ga);
        *reinterpret_cast<float4*>(&lv[row * DD + col]) =
            *reinterpret_cast<const float4*>(vbuf + ga);
    }
    __syncthreads();

    float S[DD];
    #pragma unroll
    for (int d = 0; d < DD; ++d) S[d] = 0.f;
    float P = 1.f;

    for (int t = 0; t < LCH; ++t) {
        const float ve = lv[t * DD + e];
        P *= lw[t * DD + e];
        #pragma unroll
        for (int d4 = 0; d4 < 16; ++d4) {
            const float4 k4 = *reinterpret_cast<const float4*>(&lk[t * DD + (d4 << 2)]);
            const float4 w4 = *reinterpret_cast<const float4*>(&lw[t * DD + (d4 << 2)]);
            S[(d4 << 2) + 0] = fmaf(w4.x, S[(d4 << 2) + 0], k4.x * ve);
            S[(d4 << 2) + 1] = fmaf(w4.y, S[(d4 << 2) + 1], k4.y * ve);
            S[(d4 << 2) + 2] = fmaf(w4.z, S[(d4 << 2) + 2], k4.z * ve);
            S[(d4 << 2) + 3] = fmaf(w4.w, S[(d4 << 2) + 3], k4.w * ve);
        }
    }

    float* slot = SL + (size_t)((c * BBB + b) * HH + h) * DD * DD;
    #pragma unroll
    for (int d = 0; d < DD; ++d) slot[d * DD + e] = S[d];
    Pbuf[(size_t)((c * BBB + b) * HH + h) * DD + e] = P;
}

__global__ __launch_bounds__(256)
void scanB_kernel(float* __restrict__ SL, const float* __restrict__ Pbuf)
{
    const int h = blockIdx.x, b = blockIdx.y;
    const int e  = threadIdx.x & 63;
    const int dg = threadIdx.x >> 6;

    float S[16];
    #pragma unroll
    for (int i = 0; i < 16; ++i) S[i] = 0.f;

    for (int c = 0; c < NCH; ++c) {
        float* slot = SL + (size_t)((c * BBB + b) * HH + h) * DD * DD;
        const float* pp = Pbuf + (size_t)((c * BBB + b) * HH + h) * DD;
        #pragma unroll
        for (int i = 0; i < 16; ++i) {
            const int d = dg * 16 + i;
            const float sl = slot[d * DD + e];
            S[i] = fmaf(pp[d], S[i], sl);
            slot[d * DD + e] = S[i];
        }
    }
}

__global__ __launch_bounds__(64)
void scanC_kernel(const float* __restrict__ rbuf, const float* __restrict__ kbuf,
                  const float* __restrict__ vbuf, const float* __restrict__ wbuf,
                  const float* __restrict__ gbuf, const float* __restrict__ SL,
                  const float* __restrict__ u, const float* __restrict__ lnw,
                  const float* __restrict__ lnb, u16* __restrict__ zb,
                  const int dir)
{
    __shared__ float lr[LCH * DD], lk[LCH * DD], lw[LCH * DD];
    const int c = blockIdx.x, h = blockIdx.y, b = blockIdx.z;
    const int e = threadIdx.x;
    const int rowq = e >> 4;
    const int col  = (e & 15) << 2;

    const size_t gbase = (size_t)(b * TT + c * LCH) * CC + h * DD;
    #pragma unroll
    for (int r4 = 0; r4 < 16; ++r4) {
        const int row = (r4 << 2) + rowq;
        const size_t ga = gbase + (size_t)row * CC + col;
        *reinterpret_cast<float4*>(&lr[row * DD + col]) =
            *reinterpret_cast<const float4*>(rbuf + ga);
        *reinterpret_cast<float4*>(&lk[row * DD + col]) =
            *reinterpret_cast<const float4*>(kbuf + ga);
        *reinterpret_cast<float4*>(&lw[row * DD + col]) =
            *reinterpret_cast<const float4*>(wbuf + ga);
    }
    __syncthreads();

    const float ue = u[(size_t)(dir * HH + h) * DD + e];
    const float gw = lnw[dir * CC + h * DD + e];
    const float gb = lnb[dir * CC + h * DD + e];

    float S[DD];
    if (c == 0) {
        #pragma unroll
        for (int d = 0; d < DD; ++d) S[d] = 0.f;
    } else {
        const float* slot = SL + (size_t)(((c - 1) * BBB + b) * HH + h) * DD * DD;
        #pragma unroll
        for (int d = 0; d < DD; ++d) S[d] = slot[d * DD + e];
    }

    for (int t = 0; t < LCH; ++t) {
        const float ve = vbuf[gbase + (size_t)t * CC + e];
        float coef = lr[t * DD + e] * ue * lk[t * DD + e];
        #pragma unroll
        for (int off = 32; off > 0; off >>= 1) coef += __shfl_xor(coef, off);

        float y0 = 0.f, y1 = 0.f, y2 = 0.f, y3 = 0.f;
        #pragma unroll
        for (int d4 = 0; d4 < 16; ++d4) {
            const float4 r4 = *reinterpret_cast<const float4*>(&lr[t * DD + (d4 << 2)]);
            const float4 k4 = *reinterpret_cast<const float4*>(&lk[t * DD + (d4 << 2)]);
            const float4 w4 = *reinterpret_cast<const float4*>(&lw[t * DD + (d4 << 2)]);
            y0 = fmaf(r4.x, S[(d4 << 2) + 0], y0);
            y1 = fmaf(r4.y, S[(d4 << 2) + 1], y1);
            y2 = fmaf(r4.z, S[(d4 << 2) + 2], y2);
            y3 = fmaf(r4.w, S[(d4 << 2) + 3], y3);
            S[(d4 << 2) + 0] = fmaf(w4.x, S[(d4 << 2) + 0], k4.x * ve);
            S[(d4 << 2) + 1] = fmaf(w4.y, S[(d4 << 2) + 1], k4.y * ve);
            S[(d4 << 2) + 2] = fmaf(w4.z, S[(d4 << 2) + 2], k4.z * ve);
            S[(d4 << 2) + 3] = fmaf(w4.w, S[(d4 << 2) + 3], k4.w * ve);
        }
        float y = ((y0 + y1) + (y2 + y3)) + coef * ve;

        float sum = y, sq = y * y;
        #pragma unroll
        for (int off = 32; off > 0; off >>= 1) {
            sum += __shfl_xor(sum, off);
            sq  += __shfl_xor(sq, off);
        }
        const float mean = sum * (1.f / 64.f);
        const float var  = fmaf(-mean, mean, sq * (1.f / 64.f));
        const float yn   = (y - mean) * rsqrtf(var + 1e-5f) * gw + gb;
        zb[gbase + (size_t)t * CC + e] =
            f2h(yn * gbuf[gbase + (size_t)t * CC + e]);
    }
}

extern "C" void kernel_launch(void* const* d_in, const int* in_sizes, int n_in,
                              void* d_out, int out_size, void* d_ws, size_t ws_size,
                              hipStream_t stream)
{
    const float* x     = (const float*)d_in[0];
    const void*  mask  = d_in[1];
    const float* mu    = (const float*)d_in[2];
    const float* wbias = (const float*)d_in[3];
    const float* dw1   = (const float*)d_in[4];
    const float* dw2   = (const float*)d_in[5];
    const float* u     = (const float*)d_in[6];
    const float* Wr    = (const float*)d_in[7];
    const float* Wk    = (const float*)d_in[8];
    const float* Wv    = (const float*)d_in[9];
    const float* Wg    = (const float*)d_in[10];
    const float* Wo    = (const float*)d_in[11];
    const float* lnw   = (const float*)d_in[12];
    const float* lnb   = (const float*)d_in[13];
    float* out = (float*)d_out;

    float* ws = (float*)d_ws;
    const size_t NBT = (size_t)BT * CC;
    float* rbuf  = ws;
    float* kbuf  = rbuf  + NBT;
    float* vbuf  = kbuf  + NBT;
    float* wwbuf = vbuf  + NBT;
    float* gbuf  = wwbuf + NBT;
    float* lora  = gbuf  + NBT;                       // BT*LR f32
    float* SL    = lora  + (size_t)BT * LR;           // NCH*B*H*D*D f32
    float* Pbuf  = SL    + (size_t)NCH * BBB * HH * DD * DD;
    u16*   zb    = (u16*)(Pbuf + (size_t)NCH * BBB * HH * DD);   // NBT u16
    u16*   xbb   = zb + NBT;                          // NBT u16
    u16*   wtb   = xbb + NBT;                         // 10*WSQ u16

    // prepass: weights W^T -> fp16, x -> fp16
    TP10 tj;
    const float* Wlist[5] = {Wr, Wk, Wv, Wg, Wo};
    for (int dir = 0; dir < 2; ++dir)
        for (int i = 0; i < 5; ++i)
            tj.src[dir * 5 + i] = Wlist[i] + (size_t)dir * WSQ;
    transpose_conv<<<dim3(24, 24, 10), 256, 0, stream>>>(tj, wtb);
    convert_x<<<dim3(NBT / (8 * 256)), 256, 0, stream>>>(x, xbb);

    const dim3 blk(256);
    const dim3 gridC(BT / 64, CC / 64);
    const dim3 gridL(BT / 64, LR / 64);

    for (int dir = 0; dir < 2; ++dir) {
        const float* muD = mu + (size_t)dir * 5 * CC;
        const u16* wt = wtb + (size_t)dir * 5 * WSQ;

        gemm_mfma<<<gridC, blk, 0, stream>>>(nullptr, xbb, muD + 0 * CC, wt + 0 * WSQ,
                                             nullptr, rbuf, CC, CC, dir, 0, 1);
        gemm_mfma<<<gridC, blk, 0, stream>>>(nullptr, xbb, muD + 1 * CC, wt + 1 * WSQ,
                                             nullptr, kbuf, CC, CC, dir, 0, 1);
        gemm_mfma<<<gridC, blk, 0, stream>>>(nullptr, xbb, muD + 2 * CC, wt + 2 * WSQ,
                                             nullptr, vbuf, CC, CC, dir, 0, 1);
        gemm_mfma<<<gridC, blk, 0, stream>>>(nullptr, xbb, muD + 4 * CC, wt + 3 * WSQ,
                                             nullptr, gbuf, CC, CC, dir, 1, 1);
        // decay path in fp32 (error-compounding sensitive)
        gemm_kernel<<<gridL, blk, 0, stream>>>(nullptr, x, muD + 3 * CC,
                                               dw1 + (size_t)dir * CC * LR,
                                               nullptr, lora, CC, LR, dir, 2, 1);
        gemm_kernel<<<gridC, blk, 0, stream>>>(lora, nullptr, nullptr,
                                               dw2 + (size_t)dir * LR * CC,
                                               wbias + (size_t)dir * CC,
                                               wwbuf, LR, CC, dir, 3, 0);
        scanA_kernel<<<dim3(NCH, HH, BBB), dim3(64), 0, stream>>>(
            kbuf, vbuf, wwbuf, SL, Pbuf);
        scanB_kernel<<<dim3(HH, BBB), dim3(256), 0, stream>>>(SL, Pbuf);
        scanC_kernel<<<dim3(NCH, HH, BBB), dim3(64), 0, stream>>>(
            rbuf, kbuf, vbuf, wwbuf, gbuf, SL, u, lnw, lnb, zb, dir);
        gemm_mfma<<<gridC, blk, 0, stream>>>(zb, nullptr, nullptr, wt + 4 * WSQ,
                                             mask, out, CC, CC, dir,
                                             dir == 0 ? 4 : 5, 0);
    }
}

// Round 5
// 584.517 us; speedup vs baseline: 8.5605x; 1.1276x over previous
//
#include <hip/hip_runtime.h>
#include <cstdint>
#include <cstddef>

// BiRWKV (RWKV-6 bidirectional time-mix), B=4 T=1024 C=768 H=12 D=64 LORA=64.
// Round 5: 128x128 8-wave fp16 MFMA GEMM (4 mix-GEMMs batched per dir),
// LCH=32 chunked scan (runtime fallback to 64 if ws too small),
// dedicated fp32 lora1 kernel (256 blocks). Decay path stays fp32.

#define HH   12
#define DD   64
#define CC   768
#define TT   1024
#define BBB  4
#define LR   64
#define BT   (BBB*TT)
#define WSQ  (CC*CC)

typedef unsigned short u16;
typedef _Float16 f16x8 __attribute__((ext_vector_type(8)));  // 8 f16 (4 VGPRs)
typedef float f32x4 __attribute__((ext_vector_type(4)));     // MFMA accumulator

__device__ __forceinline__ u16 f2h(float f) {
    const _Float16 h = (_Float16)f;
    return __builtin_bit_cast(u16, h);
}
__device__ __forceinline__ float h2f(u16 h) {
    return (float)__builtin_bit_cast(_Float16, h);
}

// pad_mask dtype detect (bool bytes vs int32 vs float32).
__device__ __forceinline__ float mask_val(const void* mp, int idx) {
    const unsigned char* b = (const unsigned char*)mp;
    const int i0 = ((const int*)mp)[0];
    if (i0 == 0x3f800000) {
        return ((const float*)mp)[idx] != 0.f ? 1.f : 0.f;
    }
    if ((b[1] | b[2] | b[3]) == 0) {
        return ((const int*)mp)[idx] != 0 ? 1.f : 0.f;
    }
    return b[idx] ? 1.f : 0.f;
}

// ---------------- prepass: weight transpose-convert, x convert ----------------
struct TP10 { const float* src[10]; };

// src [K=768][N=768] f32 -> dst[j][N][K] fp16 (W^T, k-contiguous rows)
__global__ __launch_bounds__(256)
void transpose_conv(TP10 tj, u16* __restrict__ dst)
{
    __shared__ float sh[32][33];
    const int j = blockIdx.z;
    const float* __restrict__ src = tj.src[j];
    u16* __restrict__ d = dst + (size_t)j * WSQ;
    const int n0 = blockIdx.x << 5, k0 = blockIdx.y << 5;
    const int tx = threadIdx.x & 31, ty = threadIdx.x >> 5;
    #pragma unroll
    for (int i = 0; i < 4; ++i)
        sh[ty + (i << 3)][tx] = src[(size_t)(k0 + ty + (i << 3)) * CC + n0 + tx];
    __syncthreads();
    #pragma unroll
    for (int i = 0; i < 4; ++i)
        d[(size_t)(n0 + ty + (i << 3)) * CC + k0 + tx] =
            f2h(sh[tx][ty + (i << 3)]);
}

__global__ __launch_bounds__(256)
void convert_x(const float* __restrict__ x, u16* __restrict__ xb)
{
    const size_t off = ((size_t)blockIdx.x * 256 + threadIdx.x) * 8;
    const float4 a = *reinterpret_cast<const float4*>(x + off);
    const float4 b = *reinterpret_cast<const float4*>(x + off + 4);
    uint4 w;
    w.x = (unsigned)f2h(a.x) | ((unsigned)f2h(a.y) << 16);
    w.y = (unsigned)f2h(a.z) | ((unsigned)f2h(a.w) << 16);
    w.z = (unsigned)f2h(b.x) | ((unsigned)f2h(b.y) << 16);
    w.w = (unsigned)f2h(b.z) | ((unsigned)f2h(b.w) << 16);
    *reinterpret_cast<uint4*>(xb + off) = w;
}

// ---------------- fp16 MFMA GEMM, 128x128 tile, 8 waves ----------------
// blockIdx.z selects slot j: {Wt, out, mu, act}. BK=64, wave = 64x32 output
// (4x2 16x16 frags). A: mixA ? token-shift lerp of fp16 x (scan-order rows)
// : fp16 buffer [BT][K]. B: Wt fp16 [N][K]. Output f32.
// act: 0 none | 1 silu | 4 store at original time order | 5 add+mask at orig.
struct GB { const u16* Wt[4]; float* out[4]; const float* mu[4]; int act[4]; };

__global__ __launch_bounds__(512)
void gemm_mfma_big(GB p, const u16* __restrict__ Ab, const u16* __restrict__ xb,
                   const void* __restrict__ mask,
                   const int K, const int N, const int dir, const int mixA)
{
    const int j = blockIdx.z;
    const u16* __restrict__ Wt = p.Wt[j];
    float* __restrict__ out = p.out[j];
    const float* __restrict__ mu = p.mu[j];
    const int act = p.act[j];

    __shared__ __align__(16) u16 Als[128][72];
    __shared__ __align__(16) u16 Bls[128][72];
    const int tid = threadIdx.x;
    const int rowbase = blockIdx.x << 7;
    const int colbase = blockIdx.y << 7;
    const int lane = tid & 63;
    const int wid = tid >> 6;           // 0..7
    const int wr = (wid >> 2) << 6;     // 0 / 64
    const int wc = (wid & 3) << 5;      // 0,32,64,96
    const int lm = lane & 15;
    const int lk = (lane >> 4) << 3;    // 0,8,16,24

    f32x4 acc[4][2] = {};

    for (int k0 = 0; k0 < K; k0 += 64) {
        #pragma unroll
        for (int it = 0; it < 2; ++it) {
            const int c   = tid + (it << 9);
            const int row = c >> 3;
            const int kq  = (c & 7) << 3;
            *reinterpret_cast<uint4*>(&Bls[row][kq]) =
                *reinterpret_cast<const uint4*>(
                    Wt + (size_t)(colbase + row) * K + k0 + kq);
            if (mixA) {
                const int s  = rowbase + row;
                const int bb = s >> 10, ts = s & (TT - 1);
                const int t  = dir ? (TT - 1 - ts) : ts;
                const int tp = dir ? (t + 1) : (t - 1);
                const uint4 xa4 = *reinterpret_cast<const uint4*>(
                    xb + (size_t)(bb * TT + t) * CC + k0 + kq);
                uint4 xp4 = make_uint4(0u, 0u, 0u, 0u);
                if (ts > 0)
                    xp4 = *reinterpret_cast<const uint4*>(
                        xb + (size_t)(bb * TT + tp) * CC + k0 + kq);
                const u16* as = reinterpret_cast<const u16*>(&xa4);
                const u16* ps = reinterpret_cast<const u16*>(&xp4);
                const float4 m0 = *reinterpret_cast<const float4*>(mu + k0 + kq);
                const float4 m1 = *reinterpret_cast<const float4*>(mu + k0 + kq + 4);
                const float mm[8] = {m0.x, m0.y, m0.z, m0.w,
                                     m1.x, m1.y, m1.z, m1.w};
                uint4 w;
                unsigned rr[4];
                #pragma unroll
                for (int q = 0; q < 4; ++q) {
                    const float a0 = h2f(as[2 * q]);
                    const float a1 = h2f(as[2 * q + 1]);
                    const float p0 = h2f(ps[2 * q]);
                    const float p1 = h2f(ps[2 * q + 1]);
                    const float v0 = fmaf(p0 - a0, mm[2 * q], a0);
                    const float v1 = fmaf(p1 - a1, mm[2 * q + 1], a1);
                    rr[q] = (unsigned)f2h(v0) | ((unsigned)f2h(v1) << 16);
                }
                w.x = rr[0]; w.y = rr[1]; w.z = rr[2]; w.w = rr[3];
                *reinterpret_cast<uint4*>(&Als[row][kq]) = w;
            } else {
                *reinterpret_cast<uint4*>(&Als[row][kq]) =
                    *reinterpret_cast<const uint4*>(
                        Ab + (size_t)(rowbase + row) * K + k0 + kq);
            }
        }
        __syncthreads();
        #pragma unroll
        for (int ks = 0; ks < 2; ++ks) {
            const int ko = (ks << 5) + lk;
            f16x8 av[4], bv[2];
            #pragma unroll
            for (int mi = 0; mi < 4; ++mi)
                av[mi] = *reinterpret_cast<const f16x8*>(&Als[wr + mi * 16 + lm][ko]);
            #pragma unroll
            for (int ni = 0; ni < 2; ++ni)
                bv[ni] = *reinterpret_cast<const f16x8*>(&Bls[wc + ni * 16 + lm][ko]);
            #pragma unroll
            for (int mi = 0; mi < 4; ++mi)
                #pragma unroll
                for (int ni = 0; ni < 2; ++ni)
                    acc[mi][ni] = __builtin_amdgcn_mfma_f32_16x16x32_f16(
                        av[mi], bv[ni], acc[mi][ni], 0, 0, 0);
        }
        __syncthreads();
    }

    // epilogue: D[m=(lane>>4)*4+r][n=lane&15] per 16x16 fragment
    #pragma unroll
    for (int mi = 0; mi < 4; ++mi) {
        #pragma unroll
        for (int r = 0; r < 4; ++r) {
            const int srow = rowbase + wr + mi * 16 + ((lane >> 4) << 2) + r;
            float v0 = acc[mi][0][r];
            float v1 = acc[mi][1][r];
            if (act == 1) {
                v0 = v0 / (1.f + expf(-v0));
                v1 = v1 / (1.f + expf(-v1));
            }
            const int col = colbase + wc + lm;
            if (act <= 1) {
                out[(size_t)srow * N + col]      = v0;
                out[(size_t)srow * N + col + 16] = v1;
            } else {
                const int b2  = srow >> 10;
                const int ts2 = srow & (TT - 1);
                const int t2  = dir ? (TT - 1 - ts2) : ts2;
                float* op = out + (size_t)(b2 * TT + t2) * CC + col;
                if (act == 4) {
                    op[0]  = v0;
                    op[16] = v1;
                } else {
                    const float mv = mask_val(mask, b2 * TT + t2);
                    op[0]  = (op[0]  + v0) * mv;
                    op[16] = (op[16] + v1) * mv;
                }
            }
        }
    }
}

// ---------------- fp32 lora1 (x-mix @ dw1, tanh), 16-row tiles ----------------
// M-tile 16, N=64, K=768, BK=64; 256 threads (4 waves); grid BT/16 = 256.
__global__ __launch_bounds__(256)
void lora1_kernel(const float* __restrict__ x, const float* __restrict__ mu,
                  const float* __restrict__ dw1, float* __restrict__ out,
                  const int dir)
{
    __shared__ float As[16][68];
    __shared__ float Bs[64][68];
    const int tid = threadIdx.x;
    const int rowbase = blockIdx.x << 4;

    const int arow = tid >> 4;            // 0..15
    const int akq  = (tid & 15) << 2;     // 0..60
    const int s  = rowbase + arow;
    const int bb = s >> 10, ts = s & (TT - 1);
    const int t  = dir ? (TT - 1 - ts) : ts;
    const int tp = dir ? (t + 1) : (t - 1);

    const int c0 = tid & 63;              // output column
    const int r4 = tid >> 6;              // wave id: row group

    float acc[4] = {0.f, 0.f, 0.f, 0.f};

    for (int k0 = 0; k0 < CC; k0 += 64) {
        {   // A tile 16x64, mixed
            const int c = k0 + akq;
            const float4 xa = *reinterpret_cast<const float4*>(
                x + (size_t)(bb * TT + t) * CC + c);
            float4 xp = make_float4(0.f, 0.f, 0.f, 0.f);
            if (ts > 0)
                xp = *reinterpret_cast<const float4*>(
                    x + (size_t)(bb * TT + tp) * CC + c);
            const float4 m4 = *reinterpret_cast<const float4*>(mu + c);
            float4 va;
            va.x = fmaf(xp.x - xa.x, m4.x, xa.x);
            va.y = fmaf(xp.y - xa.y, m4.y, xa.y);
            va.z = fmaf(xp.z - xa.z, m4.z, xa.z);
            va.w = fmaf(xp.w - xa.w, m4.w, xa.w);
            *reinterpret_cast<float4*>(&As[arow][akq]) = va;
        }
        #pragma unroll
        for (int it = 0; it < 4; ++it) {   // B tile 64x64
            const int c2 = tid + (it << 8);
            const int brow = c2 >> 4, bcol = (c2 & 15) << 2;
            *reinterpret_cast<float4*>(&Bs[brow][bcol]) =
                *reinterpret_cast<const float4*>(
                    dw1 + (size_t)(k0 + brow) * LR + bcol);
        }
        __syncthreads();
        #pragma unroll
        for (int k4 = 0; k4 < 16; ++k4) {
            float bv[4];
            #pragma unroll
            for (int q = 0; q < 4; ++q) bv[q] = Bs[(k4 << 2) + q][c0];
            #pragma unroll
            for (int i = 0; i < 4; ++i) {
                const float4 a4 = *reinterpret_cast<const float4*>(
                    &As[r4 + (i << 2)][k4 << 2]);
                acc[i] = fmaf(a4.x, bv[0], acc[i]);
                acc[i] = fmaf(a4.y, bv[1], acc[i]);
                acc[i] = fmaf(a4.z, bv[2], acc[i]);
                acc[i] = fmaf(a4.w, bv[3], acc[i]);
            }
        }
        __syncthreads();
    }
    #pragma unroll
    for (int i = 0; i < 4; ++i)
        out[(size_t)(rowbase + r4 + (i << 2)) * LR + c0] = tanhf(acc[i]);
}

// ---------------- fp32 GEMM (lora2: decay exp(-exp)) ----------------
__global__ __launch_bounds__(256)
void gemm_kernel(const float* __restrict__ Ap, const float* __restrict__ W,
                 const float* __restrict__ bias, float* __restrict__ out,
                 const int K, const int N)
{
    __shared__ float As[16][68];
    __shared__ float Bs[16][68];
    const int tid = threadIdx.x;
    const int rowbase = blockIdx.x << 6;
    const int colbase = blockIdx.y << 6;
    const int ty = tid >> 4, tx = tid & 15;
    const int am = tid >> 2;
    const int aq = tid & 3;
    const int s  = rowbase + am;
    const int bk = tid >> 4;
    const int bn = (tid & 15) << 2;

    float acc[4][4];
    #pragma unroll
    for (int i = 0; i < 4; ++i)
        #pragma unroll
        for (int j = 0; j < 4; ++j) acc[i][j] = 0.f;

    for (int k0 = 0; k0 < K; k0 += 16) {
        const float4 va = *reinterpret_cast<const float4*>(
            Ap + (size_t)s * K + k0 + (aq << 2));
        const float4 vb = *reinterpret_cast<const float4*>(
            W + (size_t)(k0 + bk) * N + colbase + bn);
        As[(aq << 2) + 0][am] = va.x;
        As[(aq << 2) + 1][am] = va.y;
        As[(aq << 2) + 2][am] = va.z;
        As[(aq << 2) + 3][am] = va.w;
        *reinterpret_cast<float4*>(&Bs[bk][bn]) = vb;
        __syncthreads();
        #pragma unroll
        for (int kk = 0; kk < 16; ++kk) {
            const float4 a  = *reinterpret_cast<const float4*>(&As[kk][ty << 2]);
            const float4 bv = *reinterpret_cast<const float4*>(&Bs[kk][tx << 2]);
            const float av[4]  = {a.x, a.y, a.z, a.w};
            const float bvv[4] = {bv.x, bv.y, bv.z, bv.w};
            #pragma unroll
            for (int i = 0; i < 4; ++i)
                #pragma unroll
                for (int j = 0; j < 4; ++j)
                    acc[i][j] = fmaf(av[i], bvv[j], acc[i][j]);
        }
        __syncthreads();
    }

    #pragma unroll
    for (int i = 0; i < 4; ++i) {
        const int srow = rowbase + (ty << 2) + i;
        const int ncol = colbase + (tx << 2);
        float v[4];
        #pragma unroll
        for (int j = 0; j < 4; ++j)
            v[j] = expf(-expf(acc[i][j] + bias[ncol + j]));
        *reinterpret_cast<float4*>(out + (size_t)srow * N + ncol) =
            make_float4(v[0], v[1], v[2], v[3]);
    }
}

// ---------------- chunked scan (A/B/C), templated chunk length ----------------
template<int L>
__global__ __launch_bounds__(64)
void scanA_kernel(const float* __restrict__ kbuf, const float* __restrict__ vbuf,
                  const float* __restrict__ wbuf,
                  float* __restrict__ SL, float* __restrict__ Pbuf)
{
    __shared__ float lk[L * DD], lw[L * DD], lv[L * DD];
    const int c = blockIdx.x, h = blockIdx.y, b = blockIdx.z;
    const int e = threadIdx.x;
    const int rowq = e >> 4;
    const int col  = (e & 15) << 2;

    const size_t gbase = (size_t)(b * TT + c * L) * CC + h * DD;
    #pragma unroll
    for (int r4 = 0; r4 < L / 4; ++r4) {
        const int row = (r4 << 2) + rowq;
        const size_t ga = gbase + (size_t)row * CC + col;
        *reinterpret_cast<float4*>(&lk[row * DD + col]) =
            *reinterpret_cast<const float4*>(kbuf + ga);
        *reinterpret_cast<float4*>(&lw[row * DD + col]) =
            *reinterpret_cast<const float4*>(wbuf + ga);
        *reinterpret_cast<float4*>(&lv[row * DD + col]) =
            *reinterpret_cast<const float4*>(vbuf + ga);
    }
    __syncthreads();

    float S[DD];
    #pragma unroll
    for (int d = 0; d < DD; ++d) S[d] = 0.f;
    float P = 1.f;

    for (int t = 0; t < L; ++t) {
        const float ve = lv[t * DD + e];
        P *= lw[t * DD + e];
        #pragma unroll
        for (int d4 = 0; d4 < 16; ++d4) {
            const float4 k4 = *reinterpret_cast<const float4*>(&lk[t * DD + (d4 << 2)]);
            const float4 w4 = *reinterpret_cast<const float4*>(&lw[t * DD + (d4 << 2)]);
            S[(d4 << 2) + 0] = fmaf(w4.x, S[(d4 << 2) + 0], k4.x * ve);
            S[(d4 << 2) + 1] = fmaf(w4.y, S[(d4 << 2) + 1], k4.y * ve);
            S[(d4 << 2) + 2] = fmaf(w4.z, S[(d4 << 2) + 2], k4.z * ve);
            S[(d4 << 2) + 3] = fmaf(w4.w, S[(d4 << 2) + 3], k4.w * ve);
        }
    }

    float* slot = SL + (size_t)((c * BBB + b) * HH + h) * DD * DD;
    #pragma unroll
    for (int d = 0; d < DD; ++d) slot[d * DD + e] = S[d];
    Pbuf[(size_t)((c * BBB + b) * HH + h) * DD + e] = P;
}

__global__ __launch_bounds__(256)
void scanB_kernel(float* __restrict__ SL, const float* __restrict__ Pbuf,
                  const int nch)
{
    const int h = blockIdx.x, b = blockIdx.y;
    const int e  = threadIdx.x & 63;
    const int dg = threadIdx.x >> 6;

    float S[16];
    #pragma unroll
    for (int i = 0; i < 16; ++i) S[i] = 0.f;

    for (int c = 0; c < nch; ++c) {
        float* slot = SL + (size_t)((c * BBB + b) * HH + h) * DD * DD;
        const float* pp = Pbuf + (size_t)((c * BBB + b) * HH + h) * DD;
        #pragma unroll
        for (int i = 0; i < 16; ++i) {
            const int d = dg * 16 + i;
            const float sl = slot[d * DD + e];
            S[i] = fmaf(pp[d], S[i], sl);
            slot[d * DD + e] = S[i];
        }
    }
}

template<int L>
__global__ __launch_bounds__(64)
void scanC_kernel(const float* __restrict__ rbuf, const float* __restrict__ kbuf,
                  const float* __restrict__ vbuf, const float* __restrict__ wbuf,
                  const float* __restrict__ gbuf, const float* __restrict__ SL,
                  const float* __restrict__ u, const float* __restrict__ lnw,
                  const float* __restrict__ lnb, u16* __restrict__ zb,
                  const int dir)
{
    __shared__ float lr[L * DD], lk[L * DD], lw[L * DD];
    const int c = blockIdx.x, h = blockIdx.y, b = blockIdx.z;
    const int e = threadIdx.x;
    const int rowq = e >> 4;
    const int col  = (e & 15) << 2;

    const size_t gbase = (size_t)(b * TT + c * L) * CC + h * DD;
    #pragma unroll
    for (int r4 = 0; r4 < L / 4; ++r4) {
        const int row = (r4 << 2) + rowq;
        const size_t ga = gbase + (size_t)row * CC + col;
        *reinterpret_cast<float4*>(&lr[row * DD + col]) =
            *reinterpret_cast<const float4*>(rbuf + ga);
        *reinterpret_cast<float4*>(&lk[row * DD + col]) =
            *reinterpret_cast<const float4*>(kbuf + ga);
        *reinterpret_cast<float4*>(&lw[row * DD + col]) =
            *reinterpret_cast<const float4*>(wbuf + ga);
    }
    __syncthreads();

    const float ue = u[(size_t)(dir * HH + h) * DD + e];
    const float gw = lnw[dir * CC + h * DD + e];
    const float gb = lnb[dir * CC + h * DD + e];

    float S[DD];
    if (c == 0) {
        #pragma unroll
        for (int d = 0; d < DD; ++d) S[d] = 0.f;
    } else {
        const float* slot = SL + (size_t)(((c - 1) * BBB + b) * HH + h) * DD * DD;
        #pragma unroll
        for (int d = 0; d < DD; ++d) S[d] = slot[d * DD + e];
    }

    for (int t = 0; t < L; ++t) {
        const float ve = vbuf[gbase + (size_t)t * CC + e];
        float coef = lr[t * DD + e] * ue * lk[t * DD + e];
        #pragma unroll
        for (int off = 32; off > 0; off >>= 1) coef += __shfl_xor(coef, off);

        float y0 = 0.f, y1 = 0.f, y2 = 0.f, y3 = 0.f;
        #pragma unroll
        for (int d4 = 0; d4 < 16; ++d4) {
            const float4 r4 = *reinterpret_cast<const float4*>(&lr[t * DD + (d4 << 2)]);
            const float4 k4 = *reinterpret_cast<const float4*>(&lk[t * DD + (d4 << 2)]);
            const float4 w4 = *reinterpret_cast<const float4*>(&lw[t * DD + (d4 << 2)]);
            y0 = fmaf(r4.x, S[(d4 << 2) + 0], y0);
            y1 = fmaf(r4.y, S[(d4 << 2) + 1], y1);
            y2 = fmaf(r4.z, S[(d4 << 2) + 2], y2);
            y3 = fmaf(r4.w, S[(d4 << 2) + 3], y3);
            S[(d4 << 2) + 0] = fmaf(w4.x, S[(d4 << 2) + 0], k4.x * ve);
            S[(d4 << 2) + 1] = fmaf(w4.y, S[(d4 << 2) + 1], k4.y * ve);
            S[(d4 << 2) + 2] = fmaf(w4.z, S[(d4 << 2) + 2], k4.z * ve);
            S[(d4 << 2) + 3] = fmaf(w4.w, S[(d4 << 2) + 3], k4.w * ve);
        }
        float y = ((y0 + y1) + (y2 + y3)) + coef * ve;

        float sum = y, sq = y * y;
        #pragma unroll
        for (int off = 32; off > 0; off >>= 1) {
            sum += __shfl_xor(sum, off);
            sq  += __shfl_xor(sq, off);
        }
        const float mean = sum * (1.f / 64.f);
        const float var  = fmaf(-mean, mean, sq * (1.f / 64.f));
        const float yn   = (y - mean) * rsqrtf(var + 1e-5f) * gw + gb;
        zb[gbase + (size_t)t * CC + e] =
            f2h(yn * gbuf[gbase + (size_t)t * CC + e]);
    }
}

extern "C" void kernel_launch(void* const* d_in, const int* in_sizes, int n_in,
                              void* d_out, int out_size, void* d_ws, size_t ws_size,
                              hipStream_t stream)
{
    const float* x     = (const float*)d_in[0];
    const void*  mask  = d_in[1];
    const float* mu    = (const float*)d_in[2];
    const float* wbias = (const float*)d_in[3];
    const float* dw1   = (const float*)d_in[4];
    const float* dw2   = (const float*)d_in[5];
    const float* u     = (const float*)d_in[6];
    const float* Wr    = (const float*)d_in[7];
    const float* Wk    = (const float*)d_in[8];
    const float* Wv    = (const float*)d_in[9];
    const float* Wg    = (const float*)d_in[10];
    const float* Wo    = (const float*)d_in[11];
    const float* lnw   = (const float*)d_in[12];
    const float* lnb   = (const float*)d_in[13];
    float* out = (float*)d_out;

    float* ws = (float*)d_ws;
    const size_t NBT = (size_t)BT * CC;

    // workspace sizing: pick 32 chunks if it fits, else 64-length chunks (16).
    auto need_bytes = [&](int nch) -> size_t {
        const size_t fl = 5 * NBT + (size_t)BT * LR
                        + (size_t)nch * BBB * HH * DD * DD
                        + (size_t)nch * BBB * HH * DD;
        const size_t hw = 2 * NBT + (size_t)10 * WSQ;
        return fl * 4 + hw * 2;
    };
    const int nch = (ws_size >= need_bytes(32)) ? 32 : 16;

    float* rbuf  = ws;
    float* kbuf  = rbuf  + NBT;
    float* vbuf  = kbuf  + NBT;
    float* wwbuf = vbuf  + NBT;
    float* gbuf  = wwbuf + NBT;
    float* lora  = gbuf  + NBT;                       // BT*LR f32
    float* SL    = lora  + (size_t)BT * LR;           // nch*B*H*D*D f32
    float* Pbuf  = SL    + (size_t)nch * BBB * HH * DD * DD;
    u16*   zb    = (u16*)(Pbuf + (size_t)nch * BBB * HH * DD);  // NBT u16
    u16*   xbb   = zb + NBT;                          // NBT u16
    u16*   wtb   = xbb + NBT;                         // 10*WSQ u16

    // prepass: weights W^T -> fp16, x -> fp16
    TP10 tj;
    const float* Wlist[5] = {Wr, Wk, Wv, Wg, Wo};
    for (int dir = 0; dir < 2; ++dir)
        for (int i = 0; i < 5; ++i)
            tj.src[dir * 5 + i] = Wlist[i] + (size_t)dir * WSQ;
    transpose_conv<<<dim3(24, 24, 10), 256, 0, stream>>>(tj, wtb);
    convert_x<<<dim3(NBT / (8 * 256)), 256, 0, stream>>>(x, xbb);

    const dim3 gridBig(BT / 128, CC / 128, 4);
    const dim3 gridOut(BT / 128, CC / 128, 1);

    for (int dir = 0; dir < 2; ++dir) {
        const float* muD = mu + (size_t)dir * 5 * CC;
        const u16* wt = wtb + (size_t)dir * 5 * WSQ;

        // batched R,K,V,G mix GEMMs
        GB pb;
        pb.Wt[0] = wt + 0 * WSQ; pb.out[0] = rbuf; pb.mu[0] = muD + 0 * CC; pb.act[0] = 0;
        pb.Wt[1] = wt + 1 * WSQ; pb.out[1] = kbuf; pb.mu[1] = muD + 1 * CC; pb.act[1] = 0;
        pb.Wt[2] = wt + 2 * WSQ; pb.out[2] = vbuf; pb.mu[2] = muD + 2 * CC; pb.act[2] = 0;
        pb.Wt[3] = wt + 3 * WSQ; pb.out[3] = gbuf; pb.mu[3] = muD + 4 * CC; pb.act[3] = 1;
        gemm_mfma_big<<<gridBig, 512, 0, stream>>>(pb, nullptr, xbb, nullptr,
                                                   CC, CC, dir, 1);

        // decay path in fp32 (error-compounding sensitive)
        lora1_kernel<<<dim3(BT / 16), 256, 0, stream>>>(x, muD + 3 * CC,
                                                        dw1 + (size_t)dir * CC * LR,
                                                        lora, dir);
        gemm_kernel<<<dim3(BT / 64, CC / 64), 256, 0, stream>>>(
            lora, dw2 + (size_t)dir * LR * CC, wbias + (size_t)dir * CC,
            wwbuf, LR, CC);

        // chunked scan
        if (nch == 32) {
            scanA_kernel<32><<<dim3(32, HH, BBB), dim3(64), 0, stream>>>(
                kbuf, vbuf, wwbuf, SL, Pbuf);
            scanB_kernel<<<dim3(HH, BBB), dim3(256), 0, stream>>>(SL, Pbuf, 32);
            scanC_kernel<32><<<dim3(32, HH, BBB), dim3(64), 0, stream>>>(
                rbuf, kbuf, vbuf, wwbuf, gbuf, SL, u, lnw, lnb, zb, dir);
        } else {
            scanA_kernel<64><<<dim3(16, HH, BBB), dim3(64), 0, stream>>>(
                kbuf, vbuf, wwbuf, SL, Pbuf);
            scanB_kernel<<<dim3(HH, BBB), dim3(256), 0, stream>>>(SL, Pbuf, 16);
            scanC_kernel<64><<<dim3(16, HH, BBB), dim3(64), 0, stream>>>(
                rbuf, kbuf, vbuf, wwbuf, gbuf, SL, u, lnw, lnb, zb, dir);
        }

        // output GEMM (+accumulate dir1, mask)
        GB po;
        po.Wt[0] = wt + 4 * WSQ; po.out[0] = out; po.mu[0] = nullptr;
        po.act[0] = (dir == 0) ? 4 : 5;
        po.Wt[1] = po.Wt[0]; po.out[1] = out; po.mu[1] = nullptr; po.act[1] = po.act[0];
        po.Wt[2] = po.Wt[0]; po.out[2] = out; po.mu[2] = nullptr; po.act[2] = po.act[0];
        po.Wt[3] = po.Wt[0]; po.out[3] = out; po.mu[3] = nullptr; po.act[3] = po.act[0];
        gemm_mfma_big<<<gridOut, 512, 0, stream>>>(po, zb, nullptr, mask,
                                                   CC, CC, dir, 0);
    }
}

// Round 6
// 512.151 us; speedup vs baseline: 9.7701x; 1.1413x over previous
//
#include <hip/hip_runtime.h>
#include <cstdint>
#include <cstddef>

// BiRWKV (RWKV-6 bidirectional time-mix), B=4 T=1024 C=768 H=12 D=64 LORA=64.
// Round 6: scanB depth-1 register prefetch + 4x d-group parallelism (breaks
// store->load false dependency that serialized 32 global round-trips);
// scanC prefetches next-step v/g. GEMMs and numerics unchanged from round 5.

#define HH   12
#define DD   64
#define CC   768
#define TT   1024
#define BBB  4
#define LR   64
#define BT   (BBB*TT)
#define WSQ  (CC*CC)

typedef unsigned short u16;
typedef _Float16 f16x8 __attribute__((ext_vector_type(8)));  // 8 f16 (4 VGPRs)
typedef float f32x4 __attribute__((ext_vector_type(4)));     // MFMA accumulator

__device__ __forceinline__ u16 f2h(float f) {
    const _Float16 h = (_Float16)f;
    return __builtin_bit_cast(u16, h);
}
__device__ __forceinline__ float h2f(u16 h) {
    return (float)__builtin_bit_cast(_Float16, h);
}

// pad_mask dtype detect (bool bytes vs int32 vs float32).
__device__ __forceinline__ float mask_val(const void* mp, int idx) {
    const unsigned char* b = (const unsigned char*)mp;
    const int i0 = ((const int*)mp)[0];
    if (i0 == 0x3f800000) {
        return ((const float*)mp)[idx] != 0.f ? 1.f : 0.f;
    }
    if ((b[1] | b[2] | b[3]) == 0) {
        return ((const int*)mp)[idx] != 0 ? 1.f : 0.f;
    }
    return b[idx] ? 1.f : 0.f;
}

// ---------------- prepass: weight transpose-convert, x convert ----------------
struct TP10 { const float* src[10]; };

// src [K=768][N=768] f32 -> dst[j][N][K] fp16 (W^T, k-contiguous rows)
__global__ __launch_bounds__(256)
void transpose_conv(TP10 tj, u16* __restrict__ dst)
{
    __shared__ float sh[32][33];
    const int j = blockIdx.z;
    const float* __restrict__ src = tj.src[j];
    u16* __restrict__ d = dst + (size_t)j * WSQ;
    const int n0 = blockIdx.x << 5, k0 = blockIdx.y << 5;
    const int tx = threadIdx.x & 31, ty = threadIdx.x >> 5;
    #pragma unroll
    for (int i = 0; i < 4; ++i)
        sh[ty + (i << 3)][tx] = src[(size_t)(k0 + ty + (i << 3)) * CC + n0 + tx];
    __syncthreads();
    #pragma unroll
    for (int i = 0; i < 4; ++i)
        d[(size_t)(n0 + ty + (i << 3)) * CC + k0 + tx] =
            f2h(sh[tx][ty + (i << 3)]);
}

__global__ __launch_bounds__(256)
void convert_x(const float* __restrict__ x, u16* __restrict__ xb)
{
    const size_t off = ((size_t)blockIdx.x * 256 + threadIdx.x) * 8;
    const float4 a = *reinterpret_cast<const float4*>(x + off);
    const float4 b = *reinterpret_cast<const float4*>(x + off + 4);
    uint4 w;
    w.x = (unsigned)f2h(a.x) | ((unsigned)f2h(a.y) << 16);
    w.y = (unsigned)f2h(a.z) | ((unsigned)f2h(a.w) << 16);
    w.z = (unsigned)f2h(b.x) | ((unsigned)f2h(b.y) << 16);
    w.w = (unsigned)f2h(b.z) | ((unsigned)f2h(b.w) << 16);
    *reinterpret_cast<uint4*>(xb + off) = w;
}

// ---------------- fp16 MFMA GEMM, 128x128 tile, 8 waves ----------------
struct GB { const u16* Wt[4]; float* out[4]; const float* mu[4]; int act[4]; };

__global__ __launch_bounds__(512)
void gemm_mfma_big(GB p, const u16* __restrict__ Ab, const u16* __restrict__ xb,
                   const void* __restrict__ mask,
                   const int K, const int N, const int dir, const int mixA)
{
    const int j = blockIdx.z;
    const u16* __restrict__ Wt = p.Wt[j];
    float* __restrict__ out = p.out[j];
    const float* __restrict__ mu = p.mu[j];
    const int act = p.act[j];

    __shared__ __align__(16) u16 Als[128][72];
    __shared__ __align__(16) u16 Bls[128][72];
    const int tid = threadIdx.x;
    const int rowbase = blockIdx.x << 7;
    const int colbase = blockIdx.y << 7;
    const int lane = tid & 63;
    const int wid = tid >> 6;           // 0..7
    const int wr = (wid >> 2) << 6;     // 0 / 64
    const int wc = (wid & 3) << 5;      // 0,32,64,96
    const int lm = lane & 15;
    const int lk = (lane >> 4) << 3;    // 0,8,16,24

    f32x4 acc[4][2] = {};

    for (int k0 = 0; k0 < K; k0 += 64) {
        #pragma unroll
        for (int it = 0; it < 2; ++it) {
            const int c   = tid + (it << 9);
            const int row = c >> 3;
            const int kq  = (c & 7) << 3;
            *reinterpret_cast<uint4*>(&Bls[row][kq]) =
                *reinterpret_cast<const uint4*>(
                    Wt + (size_t)(colbase + row) * K + k0 + kq);
            if (mixA) {
                const int s  = rowbase + row;
                const int bb = s >> 10, ts = s & (TT - 1);
                const int t  = dir ? (TT - 1 - ts) : ts;
                const int tp = dir ? (t + 1) : (t - 1);
                const uint4 xa4 = *reinterpret_cast<const uint4*>(
                    xb + (size_t)(bb * TT + t) * CC + k0 + kq);
                uint4 xp4 = make_uint4(0u, 0u, 0u, 0u);
                if (ts > 0)
                    xp4 = *reinterpret_cast<const uint4*>(
                        xb + (size_t)(bb * TT + tp) * CC + k0 + kq);
                const u16* as = reinterpret_cast<const u16*>(&xa4);
                const u16* ps = reinterpret_cast<const u16*>(&xp4);
                const float4 m0 = *reinterpret_cast<const float4*>(mu + k0 + kq);
                const float4 m1 = *reinterpret_cast<const float4*>(mu + k0 + kq + 4);
                const float mm[8] = {m0.x, m0.y, m0.z, m0.w,
                                     m1.x, m1.y, m1.z, m1.w};
                uint4 w;
                unsigned rr[4];
                #pragma unroll
                for (int q = 0; q < 4; ++q) {
                    const float a0 = h2f(as[2 * q]);
                    const float a1 = h2f(as[2 * q + 1]);
                    const float p0 = h2f(ps[2 * q]);
                    const float p1 = h2f(ps[2 * q + 1]);
                    const float v0 = fmaf(p0 - a0, mm[2 * q], a0);
                    const float v1 = fmaf(p1 - a1, mm[2 * q + 1], a1);
                    rr[q] = (unsigned)f2h(v0) | ((unsigned)f2h(v1) << 16);
                }
                w.x = rr[0]; w.y = rr[1]; w.z = rr[2]; w.w = rr[3];
                *reinterpret_cast<uint4*>(&Als[row][kq]) = w;
            } else {
                *reinterpret_cast<uint4*>(&Als[row][kq]) =
                    *reinterpret_cast<const uint4*>(
                        Ab + (size_t)(rowbase + row) * K + k0 + kq);
            }
        }
        __syncthreads();
        #pragma unroll
        for (int ks = 0; ks < 2; ++ks) {
            const int ko = (ks << 5) + lk;
            f16x8 av[4], bv[2];
            #pragma unroll
            for (int mi = 0; mi < 4; ++mi)
                av[mi] = *reinterpret_cast<const f16x8*>(&Als[wr + mi * 16 + lm][ko]);
            #pragma unroll
            for (int ni = 0; ni < 2; ++ni)
                bv[ni] = *reinterpret_cast<const f16x8*>(&Bls[wc + ni * 16 + lm][ko]);
            #pragma unroll
            for (int mi = 0; mi < 4; ++mi)
                #pragma unroll
                for (int ni = 0; ni < 2; ++ni)
                    acc[mi][ni] = __builtin_amdgcn_mfma_f32_16x16x32_f16(
                        av[mi], bv[ni], acc[mi][ni], 0, 0, 0);
        }
        __syncthreads();
    }

    #pragma unroll
    for (int mi = 0; mi < 4; ++mi) {
        #pragma unroll
        for (int r = 0; r < 4; ++r) {
            const int srow = rowbase + wr + mi * 16 + ((lane >> 4) << 2) + r;
            float v0 = acc[mi][0][r];
            float v1 = acc[mi][1][r];
            if (act == 1) {
                v0 = v0 / (1.f + expf(-v0));
                v1 = v1 / (1.f + expf(-v1));
            }
            const int col = colbase + wc + lm;
            if (act <= 1) {
                out[(size_t)srow * N + col]      = v0;
                out[(size_t)srow * N + col + 16] = v1;
            } else {
                const int b2  = srow >> 10;
                const int ts2 = srow & (TT - 1);
                const int t2  = dir ? (TT - 1 - ts2) : ts2;
                float* op = out + (size_t)(b2 * TT + t2) * CC + col;
                if (act == 4) {
                    op[0]  = v0;
                    op[16] = v1;
                } else {
                    const float mv = mask_val(mask, b2 * TT + t2);
                    op[0]  = (op[0]  + v0) * mv;
                    op[16] = (op[16] + v1) * mv;
                }
            }
        }
    }
}

// ---------------- fp32 lora1 (x-mix @ dw1, tanh), 16-row tiles ----------------
__global__ __launch_bounds__(256)
void lora1_kernel(const float* __restrict__ x, const float* __restrict__ mu,
                  const float* __restrict__ dw1, float* __restrict__ out,
                  const int dir)
{
    __shared__ float As[16][68];
    __shared__ float Bs[64][68];
    const int tid = threadIdx.x;
    const int rowbase = blockIdx.x << 4;

    const int arow = tid >> 4;
    const int akq  = (tid & 15) << 2;
    const int s  = rowbase + arow;
    const int bb = s >> 10, ts = s & (TT - 1);
    const int t  = dir ? (TT - 1 - ts) : ts;
    const int tp = dir ? (t + 1) : (t - 1);

    const int c0 = tid & 63;
    const int r4 = tid >> 6;

    float acc[4] = {0.f, 0.f, 0.f, 0.f};

    for (int k0 = 0; k0 < CC; k0 += 64) {
        {
            const int c = k0 + akq;
            const float4 xa = *reinterpret_cast<const float4*>(
                x + (size_t)(bb * TT + t) * CC + c);
            float4 xp = make_float4(0.f, 0.f, 0.f, 0.f);
            if (ts > 0)
                xp = *reinterpret_cast<const float4*>(
                    x + (size_t)(bb * TT + tp) * CC + c);
            const float4 m4 = *reinterpret_cast<const float4*>(mu + c);
            float4 va;
            va.x = fmaf(xp.x - xa.x, m4.x, xa.x);
            va.y = fmaf(xp.y - xa.y, m4.y, xa.y);
            va.z = fmaf(xp.z - xa.z, m4.z, xa.z);
            va.w = fmaf(xp.w - xa.w, m4.w, xa.w);
            *reinterpret_cast<float4*>(&As[arow][akq]) = va;
        }
        #pragma unroll
        for (int it = 0; it < 4; ++it) {
            const int c2 = tid + (it << 8);
            const int brow = c2 >> 4, bcol = (c2 & 15) << 2;
            *reinterpret_cast<float4*>(&Bs[brow][bcol]) =
                *reinterpret_cast<const float4*>(
                    dw1 + (size_t)(k0 + brow) * LR + bcol);
        }
        __syncthreads();
        #pragma unroll
        for (int k4 = 0; k4 < 16; ++k4) {
            float bv[4];
            #pragma unroll
            for (int q = 0; q < 4; ++q) bv[q] = Bs[(k4 << 2) + q][c0];
            #pragma unroll
            for (int i = 0; i < 4; ++i) {
                const float4 a4 = *reinterpret_cast<const float4*>(
                    &As[r4 + (i << 2)][k4 << 2]);
                acc[i] = fmaf(a4.x, bv[0], acc[i]);
                acc[i] = fmaf(a4.y, bv[1], acc[i]);
                acc[i] = fmaf(a4.z, bv[2], acc[i]);
                acc[i] = fmaf(a4.w, bv[3], acc[i]);
            }
        }
        __syncthreads();
    }
    #pragma unroll
    for (int i = 0; i < 4; ++i)
        out[(size_t)(rowbase + r4 + (i << 2)) * LR + c0] = tanhf(acc[i]);
}

// ---------------- fp32 GEMM (lora2: decay exp(-exp)) ----------------
__global__ __launch_bounds__(256)
void gemm_kernel(const float* __restrict__ Ap, const float* __restrict__ W,
                 const float* __restrict__ bias, float* __restrict__ out,
                 const int K, const int N)
{
    __shared__ float As[16][68];
    __shared__ float Bs[16][68];
    const int tid = threadIdx.x;
    const int rowbase = blockIdx.x << 6;
    const int colbase = blockIdx.y << 6;
    const int ty = tid >> 4, tx = tid & 15;
    const int am = tid >> 2;
    const int aq = tid & 3;
    const int s  = rowbase + am;
    const int bk = tid >> 4;
    const int bn = (tid & 15) << 2;

    float acc[4][4];
    #pragma unroll
    for (int i = 0; i < 4; ++i)
        #pragma unroll
        for (int j = 0; j < 4; ++j) acc[i][j] = 0.f;

    for (int k0 = 0; k0 < K; k0 += 16) {
        const float4 va = *reinterpret_cast<const float4*>(
            Ap + (size_t)s * K + k0 + (aq << 2));
        const float4 vb = *reinterpret_cast<const float4*>(
            W + (size_t)(k0 + bk) * N + colbase + bn);
        As[(aq << 2) + 0][am] = va.x;
        As[(aq << 2) + 1][am] = va.y;
        As[(aq << 2) + 2][am] = va.z;
        As[(aq << 2) + 3][am] = va.w;
        *reinterpret_cast<float4*>(&Bs[bk][bn]) = vb;
        __syncthreads();
        #pragma unroll
        for (int kk = 0; kk < 16; ++kk) {
            const float4 a  = *reinterpret_cast<const float4*>(&As[kk][ty << 2]);
            const float4 bv = *reinterpret_cast<const float4*>(&Bs[kk][tx << 2]);
            const float av[4]  = {a.x, a.y, a.z, a.w};
            const float bvv[4] = {bv.x, bv.y, bv.z, bv.w};
            #pragma unroll
            for (int i = 0; i < 4; ++i)
                #pragma unroll
                for (int j = 0; j < 4; ++j)
                    acc[i][j] = fmaf(av[i], bvv[j], acc[i][j]);
        }
        __syncthreads();
    }

    #pragma unroll
    for (int i = 0; i < 4; ++i) {
        const int srow = rowbase + (ty << 2) + i;
        const int ncol = colbase + (tx << 2);
        float v[4];
        #pragma unroll
        for (int j = 0; j < 4; ++j)
            v[j] = expf(-expf(acc[i][j] + bias[ncol + j]));
        *reinterpret_cast<float4*>(out + (size_t)srow * N + ncol) =
            make_float4(v[0], v[1], v[2], v[3]);
    }
}

// ---------------- chunked scan (A/B/C) ----------------
template<int L>
__global__ __launch_bounds__(64)
void scanA_kernel(const float* __restrict__ kbuf, const float* __restrict__ vbuf,
                  const float* __restrict__ wbuf,
                  float* __restrict__ SL, float* __restrict__ Pbuf)
{
    __shared__ float lk[L * DD], lw[L * DD], lv[L * DD];
    const int c = blockIdx.x, h = blockIdx.y, b = blockIdx.z;
    const int e = threadIdx.x;
    const int rowq = e >> 4;
    const int col  = (e & 15) << 2;

    const size_t gbase = (size_t)(b * TT + c * L) * CC + h * DD;
    #pragma unroll
    for (int r4 = 0; r4 < L / 4; ++r4) {
        const int row = (r4 << 2) + rowq;
        const size_t ga = gbase + (size_t)row * CC + col;
        *reinterpret_cast<float4*>(&lk[row * DD + col]) =
            *reinterpret_cast<const float4*>(kbuf + ga);
        *reinterpret_cast<float4*>(&lw[row * DD + col]) =
            *reinterpret_cast<const float4*>(wbuf + ga);
        *reinterpret_cast<float4*>(&lv[row * DD + col]) =
            *reinterpret_cast<const float4*>(vbuf + ga);
    }
    __syncthreads();

    float S[DD];
    #pragma unroll
    for (int d = 0; d < DD; ++d) S[d] = 0.f;
    float P = 1.f;

    for (int t = 0; t < L; ++t) {
        const float ve = lv[t * DD + e];
        P *= lw[t * DD + e];
        #pragma unroll
        for (int d4 = 0; d4 < 16; ++d4) {
            const float4 k4 = *reinterpret_cast<const float4*>(&lk[t * DD + (d4 << 2)]);
            const float4 w4 = *reinterpret_cast<const float4*>(&lw[t * DD + (d4 << 2)]);
            S[(d4 << 2) + 0] = fmaf(w4.x, S[(d4 << 2) + 0], k4.x * ve);
            S[(d4 << 2) + 1] = fmaf(w4.y, S[(d4 << 2) + 1], k4.y * ve);
            S[(d4 << 2) + 2] = fmaf(w4.z, S[(d4 << 2) + 2], k4.z * ve);
            S[(d4 << 2) + 3] = fmaf(w4.w, S[(d4 << 2) + 3], k4.w * ve);
        }
    }

    float* slot = SL + (size_t)((c * BBB + b) * HH + h) * DD * DD;
    #pragma unroll
    for (int d = 0; d < DD; ++d) slot[d * DD + e] = S[d];
    Pbuf[(size_t)((c * BBB + b) * HH + h) * DD + e] = P;
}

// Pass B: sequential over chunks, depth-1 register prefetch breaks the
// store->next-load false dependency. Grid (HH, BBB, 4): block owns 16 d's.
__global__ __launch_bounds__(64)
void scanB_kernel(float* __restrict__ SL, const float* __restrict__ Pbuf,
                  const int nch)
{
    const int h = blockIdx.x, b = blockIdx.y, dg = blockIdx.z;
    const int e = threadIdx.x;
    const size_t doff = (size_t)dg * 16 * DD;

    float S[16];
    #pragma unroll
    for (int i = 0; i < 16; ++i) S[i] = 0.f;

    float sl[16], pp[16];
    {
        const float* s0 = SL + (size_t)(b * HH + h) * DD * DD + doff;
        const float* p0 = Pbuf + (size_t)(b * HH + h) * DD + dg * 16;
        #pragma unroll
        for (int i = 0; i < 16; ++i) { sl[i] = s0[i * DD + e]; pp[i] = p0[i]; }
    }
    for (int c = 0; c < nch; ++c) {
        float sl2[16], pp2[16];
        if (c + 1 < nch) {    // prefetch next chunk before touching stores
            const float* s1 = SL + (size_t)(((c + 1) * BBB + b) * HH + h) * DD * DD + doff;
            const float* p1 = Pbuf + (size_t)(((c + 1) * BBB + b) * HH + h) * DD + dg * 16;
            #pragma unroll
            for (int i = 0; i < 16; ++i) { sl2[i] = s1[i * DD + e]; pp2[i] = p1[i]; }
        }
        float* sc = SL + (size_t)((c * BBB + b) * HH + h) * DD * DD + doff;
        #pragma unroll
        for (int i = 0; i < 16; ++i) {
            S[i] = fmaf(pp[i], S[i], sl[i]);
            sc[i * DD + e] = S[i];
        }
        #pragma unroll
        for (int i = 0; i < 16; ++i) { sl[i] = sl2[i]; pp[i] = pp2[i]; }
    }
}

template<int L>
__global__ __launch_bounds__(64)
void scanC_kernel(const float* __restrict__ rbuf, const float* __restrict__ kbuf,
                  const float* __restrict__ vbuf, const float* __restrict__ wbuf,
                  const float* __restrict__ gbuf, const float* __restrict__ SL,
                  const float* __restrict__ u, const float* __restrict__ lnw,
                  const float* __restrict__ lnb, u16* __restrict__ zb,
                  const int dir)
{
    __shared__ float lr[L * DD], lk[L * DD], lw[L * DD];
    const int c = blockIdx.x, h = blockIdx.y, b = blockIdx.z;
    const int e = threadIdx.x;
    const int rowq = e >> 4;
    const int col  = (e & 15) << 2;

    const size_t gbase = (size_t)(b * TT + c * L) * CC + h * DD;
    #pragma unroll
    for (int r4 = 0; r4 < L / 4; ++r4) {
        const int row = (r4 << 2) + rowq;
        const size_t ga = gbase + (size_t)row * CC + col;
        *reinterpret_cast<float4*>(&lr[row * DD + col]) =
            *reinterpret_cast<const float4*>(rbuf + ga);
        *reinterpret_cast<float4*>(&lk[row * DD + col]) =
            *reinterpret_cast<const float4*>(kbuf + ga);
        *reinterpret_cast<float4*>(&lw[row * DD + col]) =
            *reinterpret_cast<const float4*>(wbuf + ga);
    }
    __syncthreads();

    const float ue = u[(size_t)(dir * HH + h) * DD + e];
    const float gw = lnw[dir * CC + h * DD + e];
    const float gb = lnb[dir * CC + h * DD + e];

    float S[DD];
    if (c == 0) {
        #pragma unroll
        for (int d = 0; d < DD; ++d) S[d] = 0.f;
    } else {
        const float* slot = SL + (size_t)(((c - 1) * BBB + b) * HH + h) * DD * DD;
        #pragma unroll
        for (int d = 0; d < DD; ++d) S[d] = slot[d * DD + e];
    }

    float ve = vbuf[gbase + e];
    float ge = gbuf[gbase + e];
    for (int t = 0; t < L; ++t) {
        // prefetch next step's v/g (hides global latency under this step)
        float ve2 = 0.f, ge2 = 0.f;
        if (t + 1 < L) {
            ve2 = vbuf[gbase + (size_t)(t + 1) * CC + e];
            ge2 = gbuf[gbase + (size_t)(t + 1) * CC + e];
        }
        float coef = lr[t * DD + e] * ue * lk[t * DD + e];
        #pragma unroll
        for (int off = 32; off > 0; off >>= 1) coef += __shfl_xor(coef, off);

        float y0 = 0.f, y1 = 0.f, y2 = 0.f, y3 = 0.f;
        #pragma unroll
        for (int d4 = 0; d4 < 16; ++d4) {
            const float4 r4 = *reinterpret_cast<const float4*>(&lr[t * DD + (d4 << 2)]);
            const float4 k4 = *reinterpret_cast<const float4*>(&lk[t * DD + (d4 << 2)]);
            const float4 w4 = *reinterpret_cast<const float4*>(&lw[t * DD + (d4 << 2)]);
            y0 = fmaf(r4.x, S[(d4 << 2) + 0], y0);
            y1 = fmaf(r4.y, S[(d4 << 2) + 1], y1);
            y2 = fmaf(r4.z, S[(d4 << 2) + 2], y2);
            y3 = fmaf(r4.w, S[(d4 << 2) + 3], y3);
            S[(d4 << 2) + 0] = fmaf(w4.x, S[(d4 << 2) + 0], k4.x * ve);
            S[(d4 << 2) + 1] = fmaf(w4.y, S[(d4 << 2) + 1], k4.y * ve);
            S[(d4 << 2) + 2] = fmaf(w4.z, S[(d4 << 2) + 2], k4.z * ve);
            S[(d4 << 2) + 3] = fmaf(w4.w, S[(d4 << 2) + 3], k4.w * ve);
        }
        float y = ((y0 + y1) + (y2 + y3)) + coef * ve;

        float sum = y, sq = y * y;
        #pragma unroll
        for (int off = 32; off > 0; off >>= 1) {
            sum += __shfl_xor(sum, off);
            sq  += __shfl_xor(sq, off);
        }
        const float mean = sum * (1.f / 64.f);
        const float var  = fmaf(-mean, mean, sq * (1.f / 64.f));
        const float yn   = (y - mean) * rsqrtf(var + 1e-5f) * gw + gb;
        zb[gbase + (size_t)t * CC + e] = f2h(yn * ge);
        ve = ve2;
        ge = ge2;
    }
}

extern "C" void kernel_launch(void* const* d_in, const int* in_sizes, int n_in,
                              void* d_out, int out_size, void* d_ws, size_t ws_size,
                              hipStream_t stream)
{
    const float* x     = (const float*)d_in[0];
    const void*  mask  = d_in[1];
    const float* mu    = (const float*)d_in[2];
    const float* wbias = (const float*)d_in[3];
    const float* dw1   = (const float*)d_in[4];
    const float* dw2   = (const float*)d_in[5];
    const float* u     = (const float*)d_in[6];
    const float* Wr    = (const float*)d_in[7];
    const float* Wk    = (const float*)d_in[8];
    const float* Wv    = (const float*)d_in[9];
    const float* Wg    = (const float*)d_in[10];
    const float* Wo    = (const float*)d_in[11];
    const float* lnw   = (const float*)d_in[12];
    const float* lnb   = (const float*)d_in[13];
    float* out = (float*)d_out;

    float* ws = (float*)d_ws;
    const size_t NBT = (size_t)BT * CC;

    auto need_bytes = [&](int nch) -> size_t {
        const size_t fl = 5 * NBT + (size_t)BT * LR
                        + (size_t)nch * BBB * HH * DD * DD
                        + (size_t)nch * BBB * HH * DD;
        const size_t hw = 2 * NBT + (size_t)10 * WSQ;
        return fl * 4 + hw * 2;
    };
    const int nch = (ws_size >= need_bytes(32)) ? 32 : 16;

    float* rbuf  = ws;
    float* kbuf  = rbuf  + NBT;
    float* vbuf  = kbuf  + NBT;
    float* wwbuf = vbuf  + NBT;
    float* gbuf  = wwbuf + NBT;
    float* lora  = gbuf  + NBT;
    float* SL    = lora  + (size_t)BT * LR;
    float* Pbuf  = SL    + (size_t)nch * BBB * HH * DD * DD;
    u16*   zb    = (u16*)(Pbuf + (size_t)nch * BBB * HH * DD);
    u16*   xbb   = zb + NBT;
    u16*   wtb   = xbb + NBT;

    TP10 tj;
    const float* Wlist[5] = {Wr, Wk, Wv, Wg, Wo};
    for (int dir = 0; dir < 2; ++dir)
        for (int i = 0; i < 5; ++i)
            tj.src[dir * 5 + i] = Wlist[i] + (size_t)dir * WSQ;
    transpose_conv<<<dim3(24, 24, 10), 256, 0, stream>>>(tj, wtb);
    convert_x<<<dim3(NBT / (8 * 256)), 256, 0, stream>>>(x, xbb);

    const dim3 gridBig(BT / 128, CC / 128, 4);
    const dim3 gridOut(BT / 128, CC / 128, 1);

    for (int dir = 0; dir < 2; ++dir) {
        const float* muD = mu + (size_t)dir * 5 * CC;
        const u16* wt = wtb + (size_t)dir * 5 * WSQ;

        GB pb;
        pb.Wt[0] = wt + 0 * WSQ; pb.out[0] = rbuf; pb.mu[0] = muD + 0 * CC; pb.act[0] = 0;
        pb.Wt[1] = wt + 1 * WSQ; pb.out[1] = kbuf; pb.mu[1] = muD + 1 * CC; pb.act[1] = 0;
        pb.Wt[2] = wt + 2 * WSQ; pb.out[2] = vbuf; pb.mu[2] = muD + 2 * CC; pb.act[2] = 0;
        pb.Wt[3] = wt + 3 * WSQ; pb.out[3] = gbuf; pb.mu[3] = muD + 4 * CC; pb.act[3] = 1;
        gemm_mfma_big<<<gridBig, 512, 0, stream>>>(pb, nullptr, xbb, nullptr,
                                                   CC, CC, dir, 1);

        lora1_kernel<<<dim3(BT / 16), 256, 0, stream>>>(x, muD + 3 * CC,
                                                        dw1 + (size_t)dir * CC * LR,
                                                        lora, dir);
        gemm_kernel<<<dim3(BT / 64, CC / 64), 256, 0, stream>>>(
            lora, dw2 + (size_t)dir * LR * CC, wbias + (size_t)dir * CC,
            wwbuf, LR, CC);

        if (nch == 32) {
            scanA_kernel<32><<<dim3(32, HH, BBB), dim3(64), 0, stream>>>(
                kbuf, vbuf, wwbuf, SL, Pbuf);
            scanB_kernel<<<dim3(HH, BBB, 4), dim3(64), 0, stream>>>(SL, Pbuf, 32);
            scanC_kernel<32><<<dim3(32, HH, BBB), dim3(64), 0, stream>>>(
                rbuf, kbuf, vbuf, wwbuf, gbuf, SL, u, lnw, lnb, zb, dir);
        } else {
            scanA_kernel<64><<<dim3(16, HH, BBB), dim3(64), 0, stream>>>(
                kbuf, vbuf, wwbuf, SL, Pbuf);
            scanB_kernel<<<dim3(HH, BBB, 4), dim3(64), 0, stream>>>(SL, Pbuf, 16);
            scanC_kernel<64><<<dim3(16, HH, BBB), dim3(64), 0, stream>>>(
                rbuf, kbuf, vbuf, wwbuf, gbuf, SL, u, lnw, lnb, zb, dir);
        }

        GB po;
        po.Wt[0] = wt + 4 * WSQ; po.out[0] = out; po.mu[0] = nullptr;
        po.act[0] = (dir == 0) ? 4 : 5;
        po.Wt[1] = po.Wt[0]; po.out[1] = out; po.mu[1] = nullptr; po.act[1] = po.act[0];
        po.Wt[2] = po.Wt[0]; po.out[2] = out; po.mu[2] = nullptr; po.act[2] = po.act[0];
        po.Wt[3] = po.Wt[0]; po.out[3] = out; po.mu[3] = nullptr; po.act[3] = po.act[0];
        gemm_mfma_big<<<gridOut, 512, 0, stream>>>(po, zb, nullptr, mask,
                                                   CC, CC, dir, 0);
    }
}